// Round 1
// baseline (5023.608 us; speedup 1.0000x reference)
//
#include <hip/hip_runtime.h>
#include <cstdint>

using u16 = unsigned short;
using u32 = unsigned int;

#define NHEADS 3
#define WSZ 8
#define IMG 256
#define NPX 65536          // pixels per image
#define NWIN 33            // windows per side
#define ATT_SCALE 0.17677669529663687f

__device__ __forceinline__ int refl(int i, int n) {
    return i < 0 ? -i : (i >= n ? 2*n - 2 - i : i);
}
__device__ __forceinline__ float bflo(u32 u){ union{u32 i; float f;} x; x.i = u << 16; return x.f; }
__device__ __forceinline__ float bfhi(u32 u){ union{u32 i; float f;} x; x.i = u & 0xffff0000u; return x.f; }
__device__ __forceinline__ float bf2f(u16 v){ union{u32 i; float f;} x; x.i = ((u32)v) << 16; return x.f; }
__device__ __forceinline__ u16 f2bf(float f){
    union{float f; u32 i;} x; x.f = f;
    u32 r = x.i + 0x7fffu + ((x.i >> 16) & 1u);
    return (u16)(r >> 16);
}

// ---------------------------------------------------------------- bias table
// biasT[h][m][n] = bias[h][n][m]  (transposed for coalesced reads in k_attn)
__global__ __launch_bounds__(256) void k_bias(
    const float* __restrict__ m1w, const float* __restrict__ m1b,
    const float* __restrict__ m2w, const float* __restrict__ m2b,
    float* __restrict__ biasT)
{
    int idx = blockIdx.x * 256 + threadIdx.x;   // 0..12287
    int hh  = idx >> 12;
    int rem = idx & 4095;
    int n = rem >> 6, m = rem & 63;
    int di = (n >> 3) - (m >> 3);
    int dj = (n & 7)  - (m & 7);
    float fdi = copysignf(log1pf(fabsf((float)di)), (float)di);
    float fdj = copysignf(log1pf(fabsf((float)dj)), (float)dj);
    float acc = m2b[hh];
    for (int k = 0; k < 256; ++k) {
        float tv = fdi * m1w[2*k] + fdj * m1w[2*k+1] + m1b[k];
        float g  = 0.5f * tv * (1.0f + erff(tv * 0.70710678118654752f));
        acc = fmaf(g, m2w[hh*256 + k], acc);
    }
    biasT[hh*4096 + m*64 + n] = acc;
}

// ---------------------------------------------------------------- QKV 1x1 conv
// out: qkv[b][y][x][cc], cc 0..191 = QK, 192..287 = V (bf16, pixel-major)
__global__ __launch_bounds__(256, 2) void k_qkv(
    const float* __restrict__ x,
    const float* __restrict__ qkw, const float* __restrict__ qkb,
    const float* __restrict__ vw,  const float* __restrict__ vb,
    u16* __restrict__ qkv)
{
    int og   = blockIdx.x;                 // 0..2 (o-group of 96)
    int tile = blockIdx.y;                 // 0..2047
    int b    = tile >> 8;
    int pix0 = (tile & 255) * 256;
    int t    = threadIdx.x;
    int oslice = __builtin_amdgcn_readfirstlane(t >> 6);  // 0..3 (24 outs each)
    int pxg  = t & 63;
    int px   = pix0 + pxg * 4;             // 4 consecutive pixels

    const float* wbase = (og < 2) ? (qkw + og*96*96) : vw;
    const float* bbase = (og < 2) ? (qkb + og*96)    : vb;
    int obase = og * 96;

    float acc[24][4] = {};
    const float* xb = x + (size_t)b * 96 * NPX + px;

    for (int cc = 0; cc < 12; ++cc) {
        float4 xr[8];
        #pragma unroll
        for (int c = 0; c < 8; ++c)
            xr[c] = *(const float4*)(xb + (size_t)(cc*8 + c) * NPX);
        #pragma unroll
        for (int o = 0; o < 24; ++o) {
            const float* wr = wbase + (oslice*24 + o) * 96 + cc*8;
            #pragma unroll
            for (int c = 0; c < 8; ++c) {
                float w = wr[c];
                acc[o][0] = fmaf(w, xr[c].x, acc[o][0]);
                acc[o][1] = fmaf(w, xr[c].y, acc[o][1]);
                acc[o][2] = fmaf(w, xr[c].z, acc[o][2]);
                acc[o][3] = fmaf(w, xr[c].w, acc[o][3]);
            }
        }
    }
    #pragma unroll
    for (int o = 0; o < 24; ++o) {
        float bv = bbase[oslice*24 + o];
        acc[o][0] += bv; acc[o][1] += bv; acc[o][2] += bv; acc[o][3] += bv;
    }
    size_t pxbase = (size_t)b * NPX + px;
    #pragma unroll
    for (int j = 0; j < 4; ++j) {
        u16* qp = qkv + (pxbase + j) * 288 + obase + oslice*24;
        #pragma unroll
        for (int o4 = 0; o4 < 6; ++o4) {
            ushort4 sv;
            sv.x = f2bf(acc[o4*4+0][j]); sv.y = f2bf(acc[o4*4+1][j]);
            sv.z = f2bf(acc[o4*4+2][j]); sv.w = f2bf(acc[o4*4+3][j]);
            *(ushort4*)(qp + o4*4) = sv;
        }
    }
}

// ---------------------------------------------------------------- window attention
// att[b][c][y][x] bf16 (channel-major)
__global__ __launch_bounds__(192, 2) void k_attn(
    const u16* __restrict__ qkv, const float* __restrict__ biasT,
    u16* __restrict__ att)
{
    int win = blockIdx.x;               // 0..8711
    int b   = win / 1089;
    int wr  = win - b * 1089;
    int wy  = wr / NWIN;
    int wx  = wr - wy * NWIN;
    int t   = threadIdx.x;
    int h   = __builtin_amdgcn_readfirstlane(t >> 6);   // head, uniform per wave
    int n   = t & 63;

    int py = wy*8 + (n >> 3) - 4;       // original coords (pre-reflect)
    int px = wx*8 + (n & 7)  - 4;
    int iy = refl(py, IMG), ix = refl(px, IMG);

    // q row -> f32 regs
    float q[32];
    {
        const uint4* qp = (const uint4*)(qkv + ((size_t)(b*NPX + iy*256 + ix))*288 + h*32);
        u32 qu[16];
        #pragma unroll
        for (int w4 = 0; w4 < 4; ++w4) {
            uint4 v = qp[w4];
            qu[4*w4] = v.x; qu[4*w4+1] = v.y; qu[4*w4+2] = v.z; qu[4*w4+3] = v.w;
        }
        #pragma unroll
        for (int dd = 0; dd < 16; ++dd) { q[2*dd] = bflo(qu[dd]); q[2*dd+1] = bfhi(qu[dd]); }
    }

    float s[64];
    #pragma unroll
    for (int m = 0; m < 64; ++m) {
        int my = refl(wy*8 + (m >> 3) - 4, IMG);     // uniform -> s_load path
        int mx = refl(wx*8 + (m & 7)  - 4, IMG);
        const uint4* kp = (const uint4*)(qkv + ((size_t)(b*NPX + my*256 + mx))*288 + 96 + h*32);
        u32 ku[16];
        #pragma unroll
        for (int w4 = 0; w4 < 4; ++w4) {
            uint4 v = kp[w4];
            ku[4*w4] = v.x; ku[4*w4+1] = v.y; ku[4*w4+2] = v.z; ku[4*w4+3] = v.w;
        }
        float ap[4] = {0.f, 0.f, 0.f, 0.f};
        #pragma unroll
        for (int dd = 0; dd < 16; ++dd) {
            float kl = bflo(ku[dd]), kh = bfhi(ku[dd]);
            ap[dd & 3] = fmaf(q[2*dd],   kl, ap[dd & 3]);
            ap[dd & 3] = fmaf(q[2*dd+1], kh, ap[dd & 3]);
        }
        s[m] = (ap[0] + ap[1]) + (ap[2] + ap[3]);
    }

    // scale + bias, softmax (fp32)
    #pragma unroll
    for (int m = 0; m < 64; ++m)
        s[m] = fmaf(s[m], ATT_SCALE, biasT[h*4096 + m*64 + n]);

    float mx4[4] = {-1e30f, -1e30f, -1e30f, -1e30f};
    #pragma unroll
    for (int m = 0; m < 64; ++m) mx4[m & 3] = fmaxf(mx4[m & 3], s[m]);
    float mxv = fmaxf(fmaxf(mx4[0], mx4[1]), fmaxf(mx4[2], mx4[3]));

    float sm4[4] = {0.f, 0.f, 0.f, 0.f};
    #pragma unroll
    for (int m = 0; m < 64; ++m) { s[m] = __expf(s[m] - mxv); sm4[m & 3] += s[m]; }
    float inv = 1.0f / ((sm4[0] + sm4[1]) + (sm4[2] + sm4[3]));

    // PV
    float o_[32] = {};
    #pragma unroll
    for (int m = 0; m < 64; ++m) {
        int my = refl(wy*8 + (m >> 3) - 4, IMG);
        int mx = refl(wx*8 + (m & 7)  - 4, IMG);
        const uint4* vp = (const uint4*)(qkv + ((size_t)(b*NPX + my*256 + mx))*288 + 192 + h*32);
        u32 vu[16];
        #pragma unroll
        for (int w4 = 0; w4 < 4; ++w4) {
            uint4 v = vp[w4];
            vu[4*w4] = v.x; vu[4*w4+1] = v.y; vu[4*w4+2] = v.z; vu[4*w4+3] = v.w;
        }
        float p = s[m];
        #pragma unroll
        for (int dd = 0; dd < 16; ++dd) {
            o_[2*dd]   = fmaf(p, bflo(vu[dd]), o_[2*dd]);
            o_[2*dd+1] = fmaf(p, bfhi(vu[dd]), o_[2*dd+1]);
        }
    }

    if (py >= 0 && py < IMG && px >= 0 && px < IMG) {
        size_t obase = (size_t)(b*96 + h*32) * NPX + py*256 + px;
        #pragma unroll
        for (int d = 0; d < 32; ++d)
            att[obase + (size_t)d * NPX] = f2bf(o_[d] * inv);
    }
}

// ---------------------------------------------------------------- 3x3 conv + attn add
// S[b][y][x][c] bf16 (pixel-major)
__global__ __launch_bounds__(256, 2) void k_conv(
    const u16* __restrict__ qkv, const u16* __restrict__ att,
    const float* __restrict__ cw, const float* __restrict__ cb,
    u16* __restrict__ S)
{
    int tile = blockIdx.x;              // 0..2047 : tiles of 64x4 px
    int b    = tile >> 8;
    int tr   = tile & 255;
    int ty0  = (tr >> 2) * 4;
    int tx0  = (tr & 3) * 64;
    int t    = threadIdx.x;
    int oslice = __builtin_amdgcn_readfirstlane(t >> 6);
    int pxg  = t & 63;
    int lx   = (pxg & 15) * 4;          // 0..60
    int ly   = pxg >> 4;                // 0..3

    __shared__ float vt[8][6][68];
    float acc[24][4] = {};

    for (int cc = 0; cc < 12; ++cc) {
        __syncthreads();
        for (int f = t; f < 8*6*66; f += 256) {
            int c   = f / 396;
            int rem = f - c * 396;
            int r   = rem / 66;
            int xx  = rem - r * 66;
            int gy  = refl(ty0 - 1 + r,  IMG);
            int gx  = refl(tx0 - 1 + xx, IMG);
            vt[c][r][xx] = bf2f(qkv[((size_t)(b*NPX + gy*256 + gx))*288 + 192 + cc*8 + c]);
        }
        __syncthreads();

        for (int c = 0; c < 8; ++c) {
            float r_[3][6];
            #pragma unroll
            for (int dy = 0; dy < 3; ++dy) {
                float4 a4 = *(const float4*)&vt[c][ly + dy][lx];
                float2 b2 = *(const float2*)&vt[c][ly + dy][lx + 4];
                r_[dy][0] = a4.x; r_[dy][1] = a4.y; r_[dy][2] = a4.z; r_[dy][3] = a4.w;
                r_[dy][4] = b2.x; r_[dy][5] = b2.y;
            }
            #pragma unroll
            for (int o = 0; o < 24; ++o) {
                const float* wr = cw + ((size_t)(oslice*24 + o) * 96 + cc*8 + c) * 9;
                #pragma unroll
                for (int dy = 0; dy < 3; ++dy)
                    #pragma unroll
                    for (int dx = 0; dx < 3; ++dx) {
                        float w = wr[dy*3 + dx];
                        #pragma unroll
                        for (int j = 0; j < 4; ++j)
                            acc[o][j] = fmaf(w, r_[dy][j + dx], acc[o][j]);
                    }
            }
        }
    }

    int gy  = ty0 + ly;
    int gx0 = tx0 + lx;
    size_t pxi = (size_t)(b*NPX + gy*256 + gx0);
    #pragma unroll
    for (int o = 0; o < 24; ++o) {
        int oc = oslice*24 + o;
        ushort4 av = *(const ushort4*)(att + (size_t)(b*96 + oc) * NPX + gy*256 + gx0);
        float cbv = cb[oc];
        acc[o][0] += cbv + bf2f(av.x);
        acc[o][1] += cbv + bf2f(av.y);
        acc[o][2] += cbv + bf2f(av.z);
        acc[o][3] += cbv + bf2f(av.w);
    }
    #pragma unroll
    for (int j = 0; j < 4; ++j) {
        u16* sp = S + (pxi + j) * 96 + oslice*24;
        #pragma unroll
        for (int o4 = 0; o4 < 6; ++o4) {
            ushort4 sv;
            sv.x = f2bf(acc[o4*4+0][j]); sv.y = f2bf(acc[o4*4+1][j]);
            sv.z = f2bf(acc[o4*4+2][j]); sv.w = f2bf(acc[o4*4+3][j]);
            *(ushort4*)(sp + o4*4) = sv;
        }
    }
}

// ---------------------------------------------------------------- proj 1x1 conv
__global__ __launch_bounds__(256, 2) void k_proj(
    const u16* __restrict__ S,
    const float* __restrict__ pw, const float* __restrict__ pb,
    float* __restrict__ out)
{
    int tile = blockIdx.x;
    int b    = tile >> 8;
    int pix0 = (tile & 255) * 256;
    int t    = threadIdx.x;
    int oslice = __builtin_amdgcn_readfirstlane(t >> 6);
    int pxg  = t & 63;
    int px   = pix0 + pxg * 4;

    float acc[24][4] = {};
    const u16* srow = S + ((size_t)(b*NPX + px)) * 96;

    for (int cc = 0; cc < 12; ++cc) {
        float xr[8][4];
        #pragma unroll
        for (int j = 0; j < 4; ++j) {
            uint4 v = *(const uint4*)(srow + (size_t)j * 96 + cc*8);
            u32 su[4] = {v.x, v.y, v.z, v.w};
            #pragma unroll
            for (int dd = 0; dd < 4; ++dd) {
                xr[2*dd][j]   = bflo(su[dd]);
                xr[2*dd+1][j] = bfhi(su[dd]);
            }
        }
        #pragma unroll
        for (int o = 0; o < 24; ++o) {
            const float* wr = pw + (oslice*24 + o) * 96 + cc*8;
            #pragma unroll
            for (int c = 0; c < 8; ++c) {
                float w = wr[c];
                #pragma unroll
                for (int j = 0; j < 4; ++j)
                    acc[o][j] = fmaf(w, xr[c][j], acc[o][j]);
            }
        }
    }
    #pragma unroll
    for (int o = 0; o < 24; ++o) {
        int oc = oslice*24 + o;
        float bv = pb[oc];
        float4 v;
        v.x = acc[o][0] + bv; v.y = acc[o][1] + bv;
        v.z = acc[o][2] + bv; v.w = acc[o][3] + bv;
        *(float4*)(out + (size_t)(b*96 + oc) * NPX + px) = v;
    }
}

// ----------------------------------------------------------------
extern "C" void kernel_launch(void* const* d_in, const int* in_sizes, int n_in,
                              void* d_out, int out_size, void* d_ws, size_t ws_size,
                              hipStream_t stream)
{
    const float* x      = (const float*)d_in[0];
    const float* V_w    = (const float*)d_in[1];
    const float* V_b    = (const float*)d_in[2];
    const float* QK_w   = (const float*)d_in[3];
    const float* QK_b   = (const float*)d_in[4];
    const float* conv_w = (const float*)d_in[5];
    const float* conv_b = (const float*)d_in[6];
    const float* proj_w = (const float*)d_in[7];
    const float* proj_b = (const float*)d_in[8];
    const float* m1_w   = (const float*)d_in[9];
    const float* m1_b   = (const float*)d_in[10];
    const float* m2_w   = (const float*)d_in[11];
    const float* m2_b   = (const float*)d_in[12];
    float* out = (float*)d_out;

    char* ws = (char*)d_ws;
    float* biasT = (float*)ws;                                      // 49152 B
    u16* qkvb = (u16*)(ws + 49152);                                 // 301989888 B
    u16* attb = (u16*)(ws + 49152 + 301989888);                     // 100663296 B
    u16* sbuf = (u16*)(ws + 49152 + 301989888 + 100663296);         // 100663296 B

    hipLaunchKernelGGL(k_bias, dim3(48),       dim3(256), 0, stream, m1_w, m1_b, m2_w, m2_b, biasT);
    hipLaunchKernelGGL(k_qkv,  dim3(3, 2048),  dim3(256), 0, stream, x, QK_w, QK_b, V_w, V_b, qkvb);
    hipLaunchKernelGGL(k_attn, dim3(8712),     dim3(192), 0, stream, qkvb, biasT, attb);
    hipLaunchKernelGGL(k_conv, dim3(2048),     dim3(256), 0, stream, qkvb, attb, conv_w, conv_b, sbuf);
    hipLaunchKernelGGL(k_proj, dim3(2048),     dim3(256), 0, stream, sbuf, proj_w, proj_b, out);
}

// Round 2
// 2434.044 us; speedup vs baseline: 2.0639x; 2.0639x over previous
//
#include <hip/hip_runtime.h>
#include <cstdint>

using u16 = unsigned short;
using u32 = unsigned int;

#define NHEADS 3
#define WSZ 8
#define IMG 256
#define NPX 65536          // pixels per image
#define NWIN 33            // windows per side
#define ATT_SCALE 0.17677669529663687f

__device__ __forceinline__ int refl(int i, int n) {
    return i < 0 ? -i : (i >= n ? 2*n - 2 - i : i);
}
__device__ __forceinline__ float bflo(u32 u){ union{u32 i; float f;} x; x.i = u << 16; return x.f; }
__device__ __forceinline__ float bfhi(u32 u){ union{u32 i; float f;} x; x.i = u & 0xffff0000u; return x.f; }
__device__ __forceinline__ float bf2f(u16 v){ union{u32 i; float f;} x; x.i = ((u32)v) << 16; return x.f; }
__device__ __forceinline__ u16 f2bf(float f){
    union{float f; u32 i;} x; x.f = f;
    u32 r = x.i + 0x7fffu + ((x.i >> 16) & 1u);
    return (u16)(r >> 16);
}

// ---------------------------------------------------------------- bias table
// biasT[h][m][n] = bias[h][n][m]
__global__ __launch_bounds__(256) void k_bias(
    const float* __restrict__ m1w, const float* __restrict__ m1b,
    const float* __restrict__ m2w, const float* __restrict__ m2b,
    float* __restrict__ biasT)
{
    int idx = blockIdx.x * 256 + threadIdx.x;   // 0..12287
    int hh  = idx >> 12;
    int rem = idx & 4095;
    int n = rem >> 6, m = rem & 63;
    int di = (n >> 3) - (m >> 3);
    int dj = (n & 7)  - (m & 7);
    float fdi = copysignf(log1pf(fabsf((float)di)), (float)di);
    float fdj = copysignf(log1pf(fabsf((float)dj)), (float)dj);
    float acc = m2b[hh];
    for (int k = 0; k < 256; ++k) {
        float tv = fdi * m1w[2*k] + fdj * m1w[2*k+1] + m1b[k];
        float g  = 0.5f * tv * (1.0f + erff(tv * 0.70710678118654752f));
        acc = fmaf(g, m2w[hh*256 + k], acc);
    }
    biasT[hh*4096 + m*64 + n] = acc;
}

// ---------------------------------------------------------------- QKV 1x1 conv
// out: qkv[b][y][x][cc], cc 0..191 = QK, 192..287 = V (bf16, pixel-major)
__global__ __launch_bounds__(256, 2) void k_qkv(
    const float* __restrict__ x,
    const float* __restrict__ qkw, const float* __restrict__ qkb,
    const float* __restrict__ vw,  const float* __restrict__ vb,
    u16* __restrict__ qkv)
{
    int og   = blockIdx.x;                 // 0..2 (o-group of 96)
    int tile = blockIdx.y;                 // 0..2047
    int b    = tile >> 8;
    int pix0 = (tile & 255) * 256;
    int t    = threadIdx.x;
    int oslice = __builtin_amdgcn_readfirstlane(t >> 6);  // 0..3 (24 outs each)
    int pxg  = t & 63;
    int px   = pix0 + pxg * 4;             // 4 consecutive pixels

    const float* wbase = (og < 2) ? (qkw + og*96*96) : vw;
    const float* bbase = (og < 2) ? (qkb + og*96)    : vb;
    int obase = og * 96;

    float acc[24][4] = {};
    const float* xb = x + (size_t)b * 96 * NPX + px;

    for (int cc = 0; cc < 12; ++cc) {
        float4 xr[8];
        #pragma unroll
        for (int c = 0; c < 8; ++c)
            xr[c] = *(const float4*)(xb + (size_t)(cc*8 + c) * NPX);
        #pragma unroll
        for (int o = 0; o < 24; ++o) {
            const float* wr = wbase + (oslice*24 + o) * 96 + cc*8;
            #pragma unroll
            for (int c = 0; c < 8; ++c) {
                float w = wr[c];
                acc[o][0] = fmaf(w, xr[c].x, acc[o][0]);
                acc[o][1] = fmaf(w, xr[c].y, acc[o][1]);
                acc[o][2] = fmaf(w, xr[c].z, acc[o][2]);
                acc[o][3] = fmaf(w, xr[c].w, acc[o][3]);
            }
        }
    }
    #pragma unroll
    for (int o = 0; o < 24; ++o) {
        float bv = bbase[oslice*24 + o];
        acc[o][0] += bv; acc[o][1] += bv; acc[o][2] += bv; acc[o][3] += bv;
    }
    size_t pxbase = (size_t)b * NPX + px;
    #pragma unroll
    for (int j = 0; j < 4; ++j) {
        u16* qp = qkv + (pxbase + j) * 288 + obase + oslice*24;
        #pragma unroll
        for (int o4 = 0; o4 < 6; ++o4) {
            ushort4 sv;
            sv.x = f2bf(acc[o4*4+0][j]); sv.y = f2bf(acc[o4*4+1][j]);
            sv.z = f2bf(acc[o4*4+2][j]); sv.w = f2bf(acc[o4*4+3][j]);
            *(ushort4*)(qp + o4*4) = sv;
        }
    }
}

// ---------------------------------------------------------------- window attention
// one wave per (window, head); online softmax with defer-rescale (THR=8).
// att output: pixel-major [b][y][x][96] bf16
__global__ __launch_bounds__(64, 4) void k_attn(
    const u16* __restrict__ qkv, const float* __restrict__ biasT,
    u16* __restrict__ att)
{
    int win = blockIdx.x;               // 0..8711
    int h   = blockIdx.y;               // 0..2 (scalar)
    int b   = win / 1089;
    int wr  = win - b * 1089;
    int wy  = wr / NWIN;
    int wx  = wr - wy * NWIN;
    int n   = threadIdx.x;              // 0..63 query index

    int py = wy*8 + (n >> 3) - 4;       // original coords (pre-reflect)
    int px = wx*8 + (n & 7)  - 4;
    int iy = refl(py, IMG), ix = refl(px, IMG);

    // q row -> f32 regs (lane-varying load)
    float q[32];
    {
        const uint4* qp = (const uint4*)(qkv + ((size_t)(b*NPX + iy*256 + ix))*288 + h*32);
        #pragma unroll
        for (int w4 = 0; w4 < 4; ++w4) {
            uint4 v = qp[w4];
            u32 qu[4] = {v.x, v.y, v.z, v.w};
            #pragma unroll
            for (int dd = 0; dd < 4; ++dd) {
                q[w4*8 + 2*dd]     = bflo(qu[dd]);
                q[w4*8 + 2*dd + 1] = bfhi(qu[dd]);
            }
        }
    }

    float o_[32] = {};
    float mx = -1e30f, sum = 0.0f;
    const float* bp = biasT + h*4096 + n;      // + m*64 per step

    #pragma unroll 2
    for (int m = 0; m < 64; ++m) {
        int my  = refl(wy*8 + (m >> 3) - 4, IMG);    // uniform
        int mxx = refl(wx*8 + (m & 7)  - 4, IMG);    // uniform
        const u16* krow = qkv + ((size_t)(b*NPX + my*256 + mxx))*288 + 96 + h*32;

        // s = q . k  (K row is wave-uniform -> scalar loads)
        float ap0 = 0.f, ap1 = 0.f, ap2 = 0.f, ap3 = 0.f;
        #pragma unroll
        for (int w4 = 0; w4 < 4; ++w4) {
            uint4 v = ((const uint4*)krow)[w4];
            u32 ku[4] = {v.x, v.y, v.z, v.w};
            #pragma unroll
            for (int dd = 0; dd < 4; ++dd) {
                float kl = bflo(ku[dd]), kh = bfhi(ku[dd]);
                ap0 = fmaf(q[w4*8 + 2*dd],     kl, ap0);
                ap1 = fmaf(q[w4*8 + 2*dd + 1], kh, ap1);
            }
            float t2 = ap2; ap2 = ap3; ap3 = t2;   // rotate to spread deps
        }
        float s = fmaf((ap0 + ap1) + (ap2 + ap3), ATT_SCALE, bp[m*64]);

        // online softmax, defer-rescale
        float p;
        if (s <= mx + 8.0f) {
            p = __expf(s - mx);
        } else {
            float r = __expf(mx - s);
            sum *= r;
            #pragma unroll
            for (int d = 0; d < 32; ++d) o_[d] *= r;
            mx = s;
            p = 1.0f;
        }
        sum += p;

        // o_ += p * v   (V row wave-uniform)
        const u16* vrow = krow + 96;
        #pragma unroll
        for (int w4 = 0; w4 < 4; ++w4) {
            uint4 v = ((const uint4*)vrow)[w4];
            u32 vu[4] = {v.x, v.y, v.z, v.w};
            #pragma unroll
            for (int dd = 0; dd < 4; ++dd) {
                o_[w4*8 + 2*dd]     = fmaf(p, bflo(vu[dd]), o_[w4*8 + 2*dd]);
                o_[w4*8 + 2*dd + 1] = fmaf(p, bfhi(vu[dd]), o_[w4*8 + 2*dd + 1]);
            }
        }
    }

    if (py >= 0 && py < IMG && px >= 0 && px < IMG) {
        float inv = 1.0f / sum;
        u16* op = att + ((size_t)(b*NPX + py*256 + px))*96 + h*32;
        #pragma unroll
        for (int o4 = 0; o4 < 8; ++o4) {
            ushort4 sv;
            sv.x = f2bf(o_[o4*4+0] * inv); sv.y = f2bf(o_[o4*4+1] * inv);
            sv.z = f2bf(o_[o4*4+2] * inv); sv.w = f2bf(o_[o4*4+3] * inv);
            *(ushort4*)(op + o4*4) = sv;
        }
    }
}

// ---------------------------------------------------------------- 3x3 conv + attn add
// S[b][y][x][c] bf16 (pixel-major); att now pixel-major too
__global__ __launch_bounds__(256, 2) void k_conv(
    const u16* __restrict__ qkv, const u16* __restrict__ att,
    const float* __restrict__ cw, const float* __restrict__ cb,
    u16* __restrict__ S)
{
    int tile = blockIdx.x;              // 0..2047 : tiles of 64x4 px
    int b    = tile >> 8;
    int tr   = tile & 255;
    int ty0  = (tr >> 2) * 4;
    int tx0  = (tr & 3) * 64;
    int t    = threadIdx.x;
    int oslice = __builtin_amdgcn_readfirstlane(t >> 6);
    int pxg  = t & 63;
    int lx   = (pxg & 15) * 4;          // 0..60
    int ly   = pxg >> 4;                // 0..3

    __shared__ float vt[8][6][68];
    float acc[24][4] = {};

    for (int cc = 0; cc < 12; ++cc) {
        __syncthreads();
        for (int f = t; f < 8*6*66; f += 256) {
            int c   = f / 396;
            int rem = f - c * 396;
            int r   = rem / 66;
            int xx  = rem - r * 66;
            int gy  = refl(ty0 - 1 + r,  IMG);
            int gx  = refl(tx0 - 1 + xx, IMG);
            vt[c][r][xx] = bf2f(qkv[((size_t)(b*NPX + gy*256 + gx))*288 + 192 + cc*8 + c]);
        }
        __syncthreads();

        for (int c = 0; c < 8; ++c) {
            float r_[3][6];
            #pragma unroll
            for (int dy = 0; dy < 3; ++dy) {
                float4 a4 = *(const float4*)&vt[c][ly + dy][lx];
                float2 b2 = *(const float2*)&vt[c][ly + dy][lx + 4];
                r_[dy][0] = a4.x; r_[dy][1] = a4.y; r_[dy][2] = a4.z; r_[dy][3] = a4.w;
                r_[dy][4] = b2.x; r_[dy][5] = b2.y;
            }
            #pragma unroll
            for (int o = 0; o < 24; ++o) {
                const float* wr = cw + ((size_t)(oslice*24 + o) * 96 + cc*8 + c) * 9;
                #pragma unroll
                for (int dy = 0; dy < 3; ++dy)
                    #pragma unroll
                    for (int dx = 0; dx < 3; ++dx) {
                        float w = wr[dy*3 + dx];
                        #pragma unroll
                        for (int j = 0; j < 4; ++j)
                            acc[o][j] = fmaf(w, r_[dy][j + dx], acc[o][j]);
                    }
            }
        }
    }

    int gy  = ty0 + ly;
    int gx0 = tx0 + lx;
    size_t pxi = (size_t)(b*NPX + gy*256 + gx0);
    #pragma unroll
    for (int o = 0; o < 24; ++o) {
        float cbv = cb[oslice*24 + o];
        acc[o][0] += cbv; acc[o][1] += cbv; acc[o][2] += cbv; acc[o][3] += cbv;
    }
    #pragma unroll
    for (int j = 0; j < 4; ++j) {
        const u16* ap = att + (pxi + j) * 96 + oslice*24;
        u16* sp = S + (pxi + j) * 96 + oslice*24;
        #pragma unroll
        for (int o4 = 0; o4 < 6; ++o4) {
            ushort4 av = *(const ushort4*)(ap + o4*4);
            ushort4 sv;
            sv.x = f2bf(acc[o4*4+0][j] + bf2f(av.x));
            sv.y = f2bf(acc[o4*4+1][j] + bf2f(av.y));
            sv.z = f2bf(acc[o4*4+2][j] + bf2f(av.z));
            sv.w = f2bf(acc[o4*4+3][j] + bf2f(av.w));
            *(ushort4*)(sp + o4*4) = sv;
        }
    }
}

// ---------------------------------------------------------------- proj 1x1 conv
__global__ __launch_bounds__(256, 2) void k_proj(
    const u16* __restrict__ S,
    const float* __restrict__ pw, const float* __restrict__ pb,
    float* __restrict__ out)
{
    int tile = blockIdx.x;
    int b    = tile >> 8;
    int pix0 = (tile & 255) * 256;
    int t    = threadIdx.x;
    int oslice = __builtin_amdgcn_readfirstlane(t >> 6);
    int pxg  = t & 63;
    int px   = pix0 + pxg * 4;

    float acc[24][4] = {};
    const u16* srow = S + ((size_t)(b*NPX + px)) * 96;

    for (int cc = 0; cc < 12; ++cc) {
        float xr[8][4];
        #pragma unroll
        for (int j = 0; j < 4; ++j) {
            uint4 v = *(const uint4*)(srow + (size_t)j * 96 + cc*8);
            u32 su[4] = {v.x, v.y, v.z, v.w};
            #pragma unroll
            for (int dd = 0; dd < 4; ++dd) {
                xr[2*dd][j]   = bflo(su[dd]);
                xr[2*dd+1][j] = bfhi(su[dd]);
            }
        }
        #pragma unroll
        for (int o = 0; o < 24; ++o) {
            const float* wr = pw + (oslice*24 + o) * 96 + cc*8;
            #pragma unroll
            for (int c = 0; c < 8; ++c) {
                float w = wr[c];
                #pragma unroll
                for (int j = 0; j < 4; ++j)
                    acc[o][j] = fmaf(w, xr[c][j], acc[o][j]);
            }
        }
    }
    #pragma unroll
    for (int o = 0; o < 24; ++o) {
        int oc = oslice*24 + o;
        float bv = pb[oc];
        float4 v;
        v.x = acc[o][0] + bv; v.y = acc[o][1] + bv;
        v.z = acc[o][2] + bv; v.w = acc[o][3] + bv;
        *(float4*)(out + (size_t)(b*96 + oc) * NPX + px) = v;
    }
}

// ----------------------------------------------------------------
extern "C" void kernel_launch(void* const* d_in, const int* in_sizes, int n_in,
                              void* d_out, int out_size, void* d_ws, size_t ws_size,
                              hipStream_t stream)
{
    const float* x      = (const float*)d_in[0];
    const float* V_w    = (const float*)d_in[1];
    const float* V_b    = (const float*)d_in[2];
    const float* QK_w   = (const float*)d_in[3];
    const float* QK_b   = (const float*)d_in[4];
    const float* conv_w = (const float*)d_in[5];
    const float* conv_b = (const float*)d_in[6];
    const float* proj_w = (const float*)d_in[7];
    const float* proj_b = (const float*)d_in[8];
    const float* m1_w   = (const float*)d_in[9];
    const float* m1_b   = (const float*)d_in[10];
    const float* m2_w   = (const float*)d_in[11];
    const float* m2_b   = (const float*)d_in[12];
    float* out = (float*)d_out;

    char* ws = (char*)d_ws;
    float* biasT = (float*)ws;                                      // 49152 B
    u16* qkvb = (u16*)(ws + 49152);                                 // 301989888 B
    u16* attb = (u16*)(ws + 49152 + 301989888);                     // 100663296 B
    u16* sbuf = (u16*)(ws + 49152 + 301989888 + 100663296);         // 100663296 B

    hipLaunchKernelGGL(k_bias, dim3(48),       dim3(256), 0, stream, m1_w, m1_b, m2_w, m2_b, biasT);
    hipLaunchKernelGGL(k_qkv,  dim3(3, 2048),  dim3(256), 0, stream, x, QK_w, QK_b, V_w, V_b, qkvb);
    hipLaunchKernelGGL(k_attn, dim3(8712, 3),  dim3(64),  0, stream, qkvb, biasT, attb);
    hipLaunchKernelGGL(k_conv, dim3(2048),     dim3(256), 0, stream, qkvb, attb, conv_w, conv_b, sbuf);
    hipLaunchKernelGGL(k_proj, dim3(2048),     dim3(256), 0, stream, sbuf, proj_w, proj_b, out);
}

// Round 3
// 1327.640 us; speedup vs baseline: 3.7839x; 1.8334x over previous
//
#include <hip/hip_runtime.h>
#include <cstdint>

using u16 = unsigned short;
using u32 = unsigned int;
using f32x4  = __attribute__((ext_vector_type(4))) float;
using bf16x8 = __attribute__((ext_vector_type(8))) short;

#define NHEADS 3
#define WSZ 8
#define IMG 256
#define NPX 65536          // pixels per image
#define NWIN 33            // windows per side
#define ATT_SCALE 0.17677669529663687f
#define HALO_PITCH 104     // u16 per halo pixel (208 B: 96 ch + 8 pad -> conflict-free)

__device__ __forceinline__ int refl(int i, int n) {
    return i < 0 ? -i : (i >= n ? 2*n - 2 - i : i);
}
__device__ __forceinline__ float bflo(u32 u){ union{u32 i; float f;} x; x.i = u << 16; return x.f; }
__device__ __forceinline__ float bfhi(u32 u){ union{u32 i; float f;} x; x.i = u & 0xffff0000u; return x.f; }
__device__ __forceinline__ float bf2f(u16 v){ union{u32 i; float f;} x; x.i = ((u32)v) << 16; return x.f; }
__device__ __forceinline__ u16 f2bf(float f){
    union{float f; u32 i;} x; x.f = f;
    u32 r = x.i + 0x7fffu + ((x.i >> 16) & 1u);
    return (u16)(r >> 16);
}

// ---------------------------------------------------------------- bias table
// biasT[h][m][n] = bias[h][n][m]
__global__ __launch_bounds__(256) void k_bias(
    const float* __restrict__ m1w, const float* __restrict__ m1b,
    const float* __restrict__ m2w, const float* __restrict__ m2b,
    float* __restrict__ biasT)
{
    int idx = blockIdx.x * 256 + threadIdx.x;   // 0..12287
    int hh  = idx >> 12;
    int rem = idx & 4095;
    int n = rem >> 6, m = rem & 63;
    int di = (n >> 3) - (m >> 3);
    int dj = (n & 7)  - (m & 7);
    float fdi = copysignf(log1pf(fabsf((float)di)), (float)di);
    float fdj = copysignf(log1pf(fabsf((float)dj)), (float)dj);
    float acc = m2b[hh];
    for (int k = 0; k < 256; ++k) {
        float tv = fdi * m1w[2*k] + fdj * m1w[2*k+1] + m1b[k];
        float g  = 0.5f * tv * (1.0f + erff(tv * 0.70710678118654752f));
        acc = fmaf(g, m2w[hh*256 + k], acc);
    }
    biasT[hh*4096 + m*64 + n] = acc;
}

// ---------------------------------------------------------------- conv weight pre-pack
// Bfrag[(ck*9+tap)*6+nt][lane][j] = bf16( w[nt*16+(lane&15)][ck*32+(lane>>4)*8+j][dy][dx] )
__global__ __launch_bounds__(64) void k_wprep(
    const float* __restrict__ cw, u16* __restrict__ Bfrag)
{
    int ks   = blockIdx.x;        // 0..161 = (ck*9+tap)*6+nt
    int lane = threadIdx.x;
    int nt    = ks % 6;
    int kstep = ks / 6;
    int tap   = kstep % 9;
    int ck    = kstep / 9;
    int dy = tap / 3, dx = tap % 3;
    int cout = nt*16 + (lane & 15);
    int cin0 = ck*32 + (lane >> 4)*8;
    u16* dst = Bfrag + (size_t)ks*512 + lane*8;
    #pragma unroll
    for (int j = 0; j < 8; ++j)
        dst[j] = f2bf(cw[((size_t)(cout*96 + cin0 + j))*9 + dy*3 + dx]);
}

// ---------------------------------------------------------------- QKV 1x1 conv
// out: qkv[b][y][x][cc], cc 0..191 = QK, 192..287 = V (bf16, pixel-major)
__global__ __launch_bounds__(256, 2) void k_qkv(
    const float* __restrict__ x,
    const float* __restrict__ qkw, const float* __restrict__ qkb,
    const float* __restrict__ vw,  const float* __restrict__ vb,
    u16* __restrict__ qkv)
{
    int og   = blockIdx.x;                 // 0..2 (o-group of 96)
    int tile = blockIdx.y;                 // 0..2047
    int b    = tile >> 8;
    int pix0 = (tile & 255) * 256;
    int t    = threadIdx.x;
    int oslice = __builtin_amdgcn_readfirstlane(t >> 6);  // 0..3 (24 outs each)
    int pxg  = t & 63;
    int px   = pix0 + pxg * 4;             // 4 consecutive pixels

    const float* wbase = (og < 2) ? (qkw + og*96*96) : vw;
    const float* bbase = (og < 2) ? (qkb + og*96)    : vb;
    int obase = og * 96;

    float acc[24][4] = {};
    const float* xb = x + (size_t)b * 96 * NPX + px;

    for (int cc = 0; cc < 12; ++cc) {
        float4 xr[8];
        #pragma unroll
        for (int c = 0; c < 8; ++c)
            xr[c] = *(const float4*)(xb + (size_t)(cc*8 + c) * NPX);
        #pragma unroll
        for (int o = 0; o < 24; ++o) {
            const float* wr = wbase + (oslice*24 + o) * 96 + cc*8;
            #pragma unroll
            for (int c = 0; c < 8; ++c) {
                float w = wr[c];
                acc[o][0] = fmaf(w, xr[c].x, acc[o][0]);
                acc[o][1] = fmaf(w, xr[c].y, acc[o][1]);
                acc[o][2] = fmaf(w, xr[c].z, acc[o][2]);
                acc[o][3] = fmaf(w, xr[c].w, acc[o][3]);
            }
        }
    }
    #pragma unroll
    for (int o = 0; o < 24; ++o) {
        float bv = bbase[oslice*24 + o];
        acc[o][0] += bv; acc[o][1] += bv; acc[o][2] += bv; acc[o][3] += bv;
    }
    size_t pxbase = (size_t)b * NPX + px;
    #pragma unroll
    for (int j = 0; j < 4; ++j) {
        u16* qp = qkv + (pxbase + j) * 288 + obase + oslice*24;
        #pragma unroll
        for (int o4 = 0; o4 < 6; ++o4) {
            ushort4 sv;
            sv.x = f2bf(acc[o4*4+0][j]); sv.y = f2bf(acc[o4*4+1][j]);
            sv.z = f2bf(acc[o4*4+2][j]); sv.w = f2bf(acc[o4*4+3][j]);
            *(ushort4*)(qp + o4*4) = sv;
        }
    }
}

// ---------------------------------------------------------------- window attention
// one wave per (window, head); online softmax with defer-rescale (THR=8).
// att output: pixel-major [b][y][x][96] bf16
__global__ __launch_bounds__(64, 4) void k_attn(
    const u16* __restrict__ qkv, const float* __restrict__ biasT,
    u16* __restrict__ att)
{
    int win = blockIdx.x;               // 0..8711
    int h   = blockIdx.y;               // 0..2 (scalar)
    int b   = win / 1089;
    int wr  = win - b * 1089;
    int wy  = wr / NWIN;
    int wx  = wr - wy * NWIN;
    int n   = threadIdx.x;              // 0..63 query index

    int py = wy*8 + (n >> 3) - 4;       // original coords (pre-reflect)
    int px = wx*8 + (n & 7)  - 4;
    int iy = refl(py, IMG), ix = refl(px, IMG);

    // q row -> f32 regs (lane-varying load)
    float q[32];
    {
        const uint4* qp = (const uint4*)(qkv + ((size_t)(b*NPX + iy*256 + ix))*288 + h*32);
        #pragma unroll
        for (int w4 = 0; w4 < 4; ++w4) {
            uint4 v = qp[w4];
            u32 qu[4] = {v.x, v.y, v.z, v.w};
            #pragma unroll
            for (int dd = 0; dd < 4; ++dd) {
                q[w4*8 + 2*dd]     = bflo(qu[dd]);
                q[w4*8 + 2*dd + 1] = bfhi(qu[dd]);
            }
        }
    }

    float o_[32] = {};
    float mx = -1e30f, sum = 0.0f;
    const float* bp = biasT + h*4096 + n;      // + m*64 per step

    #pragma unroll 2
    for (int m = 0; m < 64; ++m) {
        int my  = refl(wy*8 + (m >> 3) - 4, IMG);    // uniform
        int mxx = refl(wx*8 + (m & 7)  - 4, IMG);    // uniform
        const u16* krow = qkv + ((size_t)(b*NPX + my*256 + mxx))*288 + 96 + h*32;

        // s = q . k  (K row is wave-uniform -> scalar loads)
        float ap0 = 0.f, ap1 = 0.f, ap2 = 0.f, ap3 = 0.f;
        #pragma unroll
        for (int w4 = 0; w4 < 4; ++w4) {
            uint4 v = ((const uint4*)krow)[w4];
            u32 ku[4] = {v.x, v.y, v.z, v.w};
            #pragma unroll
            for (int dd = 0; dd < 4; ++dd) {
                float kl = bflo(ku[dd]), kh = bfhi(ku[dd]);
                ap0 = fmaf(q[w4*8 + 2*dd],     kl, ap0);
                ap1 = fmaf(q[w4*8 + 2*dd + 1], kh, ap1);
            }
            float t2 = ap2; ap2 = ap3; ap3 = t2;   // rotate to spread deps
        }
        float s = fmaf((ap0 + ap1) + (ap2 + ap3), ATT_SCALE, bp[m*64]);

        // online softmax, defer-rescale
        float p;
        if (s <= mx + 8.0f) {
            p = __expf(s - mx);
        } else {
            float r = __expf(mx - s);
            sum *= r;
            #pragma unroll
            for (int d = 0; d < 32; ++d) o_[d] *= r;
            mx = s;
            p = 1.0f;
        }
        sum += p;

        // o_ += p * v   (V row wave-uniform)
        const u16* vrow = krow + 96;
        #pragma unroll
        for (int w4 = 0; w4 < 4; ++w4) {
            uint4 v = ((const uint4*)vrow)[w4];
            u32 vu[4] = {v.x, v.y, v.z, v.w};
            #pragma unroll
            for (int dd = 0; dd < 4; ++dd) {
                o_[w4*8 + 2*dd]     = fmaf(p, bflo(vu[dd]), o_[w4*8 + 2*dd]);
                o_[w4*8 + 2*dd + 1] = fmaf(p, bfhi(vu[dd]), o_[w4*8 + 2*dd + 1]);
            }
        }
    }

    if (py >= 0 && py < IMG && px >= 0 && px < IMG) {
        float inv = 1.0f / sum;
        u16* op = att + ((size_t)(b*NPX + py*256 + px))*96 + h*32;
        #pragma unroll
        for (int o4 = 0; o4 < 8; ++o4) {
            ushort4 sv;
            sv.x = f2bf(o_[o4*4+0] * inv); sv.y = f2bf(o_[o4*4+1] * inv);
            sv.z = f2bf(o_[o4*4+2] * inv); sv.w = f2bf(o_[o4*4+3] * inv);
            *(ushort4*)(op + o4*4) = sv;
        }
    }
}

// ---------------------------------------------------------------- 3x3 conv + attn add (MFMA)
// block: 8x32 px output tile, 96 cout. LDS: 10x34 halo x 96ch bf16, 208B pitch.
// K = 3 cin-chunks x 9 taps x K32. Wave w: rows {2w,2w+1}, acc 4mt x 6nt.
__global__ __launch_bounds__(256, 1) void k_conv(
    const u16* __restrict__ qkv, const u16* __restrict__ att,
    const u16* __restrict__ Bfrag, const float* __restrict__ cb,
    u16* __restrict__ S)
{
    int tile = blockIdx.x;              // 0..2047
    int b    = tile >> 8;
    int tr   = tile & 255;              // 32 row-tiles x 8 col-tiles
    int ty0  = (tr >> 3) * 8;
    int tx0  = (tr & 7) * 32;
    int t    = threadIdx.x;

    __shared__ u16 vt[340 * HALO_PITCH];   // 70,720 B

    // stage halo (10x34 px, 96 ch each) -> LDS, bf16
    for (int p = t; p < 340; p += 256) {
        int hr = p / 34;
        int hc = p - hr * 34;
        int gy = refl(ty0 - 1 + hr, IMG);
        int gx = refl(tx0 - 1 + hc, IMG);
        const uint4* src = (const uint4*)(qkv + ((size_t)(b*NPX + gy*256 + gx))*288 + 192);
        uint4* dst = (uint4*)(vt + p * HALO_PITCH);
        #pragma unroll
        for (int q = 0; q < 12; ++q) dst[q] = src[q];
    }
    __syncthreads();

    int wv   = __builtin_amdgcn_readfirstlane(t >> 6);
    int lane = t & 63;
    int lc   = lane & 15;
    int kg   = lane >> 4;

    int abase[4];
    #pragma unroll
    for (int mt = 0; mt < 4; ++mt) {
        int r_mt = 2*wv + (mt >> 1);
        int c_mt = (mt & 1) * 16;
        abase[mt] = (r_mt*34 + c_mt + lc) * HALO_PITCH + kg*8;
    }

    f32x4 acc[4][6] = {};

    const u16* bfr = Bfrag + lane*8;
    #pragma unroll 1
    for (int ck = 0; ck < 3; ++ck) {
        const u16* bck = bfr + ck * 27648;     // ck * 9 taps * 6 nt * 512
        int aoff = ck * 32;
        #pragma unroll
        for (int tap = 0; tap < 9; ++tap) {
            const int dy = tap / 3, dx = tap % 3;
            bf16x8 bF[6];
            #pragma unroll
            for (int nt = 0; nt < 6; ++nt)
                bF[nt] = *(const bf16x8*)(bck + (tap*6 + nt)*512);
            #pragma unroll
            for (int mt = 0; mt < 4; ++mt) {
                bf16x8 aF = *(const bf16x8*)(vt + abase[mt] + aoff + (dy*34 + dx)*HALO_PITCH);
                #pragma unroll
                for (int nt = 0; nt < 6; ++nt)
                    acc[mt][nt] = __builtin_amdgcn_mfma_f32_16x16x32_bf16(aF, bF[nt], acc[mt][nt], 0, 0, 0);
            }
        }
    }

    // epilogue: + conv bias + attn, store bf16 pixel-major
    float cbv[6];
    #pragma unroll
    for (int nt = 0; nt < 6; ++nt) cbv[nt] = cb[nt*16 + lc];

    #pragma unroll
    for (int mt = 0; mt < 4; ++mt) {
        int r_mt = 2*wv + (mt >> 1);
        int c_mt = (mt & 1) * 16;
        int y    = ty0 + r_mt;
        #pragma unroll
        for (int r = 0; r < 4; ++r) {
            int x = tx0 + c_mt + kg*4 + r;          // C row = kg*4 + r -> pixel within mtile
            size_t pbase = ((size_t)(b*NPX + y*256 + x))*96 + lc;
            #pragma unroll
            for (int nt = 0; nt < 6; ++nt) {
                float v = acc[mt][nt][r] + cbv[nt] + bf2f(att[pbase + nt*16]);
                S[pbase + nt*16] = f2bf(v);
            }
        }
    }
}

// ---------------------------------------------------------------- proj 1x1 conv
__global__ __launch_bounds__(256, 2) void k_proj(
    const u16* __restrict__ S,
    const float* __restrict__ pw, const float* __restrict__ pb,
    float* __restrict__ out)
{
    int tile = blockIdx.x;
    int b    = tile >> 8;
    int pix0 = (tile & 255) * 256;
    int t    = threadIdx.x;
    int oslice = __builtin_amdgcn_readfirstlane(t >> 6);
    int pxg  = t & 63;
    int px   = pix0 + pxg * 4;

    float acc[24][4] = {};
    const u16* srow = S + ((size_t)(b*NPX + px)) * 96;

    for (int cc = 0; cc < 12; ++cc) {
        float xr[8][4];
        #pragma unroll
        for (int j = 0; j < 4; ++j) {
            uint4 v = *(const uint4*)(srow + (size_t)j * 96 + cc*8);
            u32 su[4] = {v.x, v.y, v.z, v.w};
            #pragma unroll
            for (int dd = 0; dd < 4; ++dd) {
                xr[2*dd][j]   = bflo(su[dd]);
                xr[2*dd+1][j] = bfhi(su[dd]);
            }
        }
        #pragma unroll
        for (int o = 0; o < 24; ++o) {
            const float* wr = pw + (oslice*24 + o) * 96 + cc*8;
            #pragma unroll
            for (int c = 0; c < 8; ++c) {
                float w = wr[c];
                #pragma unroll
                for (int j = 0; j < 4; ++j)
                    acc[o][j] = fmaf(w, xr[c][j], acc[o][j]);
            }
        }
    }
    #pragma unroll
    for (int o = 0; o < 24; ++o) {
        int oc = oslice*24 + o;
        float bv = pb[oc];
        float4 v;
        v.x = acc[o][0] + bv; v.y = acc[o][1] + bv;
        v.z = acc[o][2] + bv; v.w = acc[o][3] + bv;
        *(float4*)(out + (size_t)(b*96 + oc) * NPX + px) = v;
    }
}

// ----------------------------------------------------------------
extern "C" void kernel_launch(void* const* d_in, const int* in_sizes, int n_in,
                              void* d_out, int out_size, void* d_ws, size_t ws_size,
                              hipStream_t stream)
{
    const float* x      = (const float*)d_in[0];
    const float* V_w    = (const float*)d_in[1];
    const float* V_b    = (const float*)d_in[2];
    const float* QK_w   = (const float*)d_in[3];
    const float* QK_b   = (const float*)d_in[4];
    const float* conv_w = (const float*)d_in[5];
    const float* conv_b = (const float*)d_in[6];
    const float* proj_w = (const float*)d_in[7];
    const float* proj_b = (const float*)d_in[8];
    const float* m1_w   = (const float*)d_in[9];
    const float* m1_b   = (const float*)d_in[10];
    const float* m2_w   = (const float*)d_in[11];
    const float* m2_b   = (const float*)d_in[12];
    float* out = (float*)d_out;

    char* ws = (char*)d_ws;
    float* biasT = (float*)ws;                                      // 49152 B
    u16* qkvb = (u16*)(ws + 49152);                                 // 301989888 B
    u16* attb = (u16*)(ws + 49152 + 301989888);                     // 100663296 B
    u16* sbuf = (u16*)(ws + 49152 + 301989888 + 100663296);         // 100663296 B

    // conv weight fragments live at the head of d_out (332 KB scratch);
    // k_proj overwrites d_out only after k_conv has consumed them (stream order).
    u16* Bfrag = (u16*)d_out;

    hipLaunchKernelGGL(k_wprep, dim3(162),      dim3(64),  0, stream, conv_w, Bfrag);
    hipLaunchKernelGGL(k_bias,  dim3(48),       dim3(256), 0, stream, m1_w, m1_b, m2_w, m2_b, biasT);
    hipLaunchKernelGGL(k_qkv,   dim3(3, 2048),  dim3(256), 0, stream, x, QK_w, QK_b, V_w, V_b, qkvb);
    hipLaunchKernelGGL(k_attn,  dim3(8712, 3),  dim3(64),  0, stream, qkvb, biasT, attb);
    hipLaunchKernelGGL(k_conv,  dim3(2048),     dim3(256), 0, stream, qkvb, attb, Bfrag, conv_b, sbuf);
    hipLaunchKernelGGL(k_proj,  dim3(2048),     dim3(256), 0, stream, sbuf, proj_w, proj_b, out);
}

// Round 4
// 1064.047 us; speedup vs baseline: 4.7212x; 1.2477x over previous
//
#include <hip/hip_runtime.h>
#include <cstdint>

using u16 = unsigned short;
using u32 = unsigned int;
using f32x4  = __attribute__((ext_vector_type(4))) float;
using bf16x8 = __attribute__((ext_vector_type(8))) short;

#define NHEADS 3
#define WSZ 8
#define IMG 256
#define NPX 65536          // pixels per image
#define NWIN 33            // windows per side
#define ATT_SCALE 0.17677669529663687f
#define HALO_PITCH 104     // u16 per halo pixel (208 B: 96 ch + 8 pad -> conflict-free)

__device__ __forceinline__ int refl(int i, int n) {
    return i < 0 ? -i : (i >= n ? 2*n - 2 - i : i);
}
__device__ __forceinline__ float bflo(u32 u){ union{u32 i; float f;} x; x.i = u << 16; return x.f; }
__device__ __forceinline__ float bfhi(u32 u){ union{u32 i; float f;} x; x.i = u & 0xffff0000u; return x.f; }
__device__ __forceinline__ float bf2f(u16 v){ union{u32 i; float f;} x; x.i = ((u32)v) << 16; return x.f; }
__device__ __forceinline__ u16 f2bf(float f){
    union{float f; u32 i;} x; x.f = f;
    u32 r = x.i + 0x7fffu + ((x.i >> 16) & 1u);
    return (u16)(r >> 16);
}
__device__ __forceinline__ u32 pk2bf(float a, float b){
    return (u32)f2bf(a) | ((u32)f2bf(b) << 16);
}

// ---------------------------------------------------------------- bias table
// biasT[h][m][n] = bias[h][n][m]
__global__ __launch_bounds__(256) void k_bias(
    const float* __restrict__ m1w, const float* __restrict__ m1b,
    const float* __restrict__ m2w, const float* __restrict__ m2b,
    float* __restrict__ biasT)
{
    int idx = blockIdx.x * 256 + threadIdx.x;   // 0..12287
    int hh  = idx >> 12;
    int rem = idx & 4095;
    int n = rem >> 6, m = rem & 63;
    int di = (n >> 3) - (m >> 3);
    int dj = (n & 7)  - (m & 7);
    float fdi = copysignf(log1pf(fabsf((float)di)), (float)di);
    float fdj = copysignf(log1pf(fabsf((float)dj)), (float)dj);
    float acc = m2b[hh];
    for (int k = 0; k < 256; ++k) {
        float tv = fdi * m1w[2*k] + fdj * m1w[2*k+1] + m1b[k];
        float g  = 0.5f * tv * (1.0f + erff(tv * 0.70710678118654752f));
        acc = fmaf(g, m2w[hh*256 + k], acc);
    }
    biasT[hh*4096 + m*64 + n] = acc;
}

// ---------------------------------------------------------------- x transpose: [b][c][px] f32 -> [b*px][96] bf16
__global__ __launch_bounds__(256, 4) void k_xt(
    const float* __restrict__ x, u16* __restrict__ xt)
{
    int blk = blockIdx.x;            // 0..2047
    int b   = blk >> 8;
    int pt  = blk & 255;
    int px  = pt*256 + threadIdx.x;
    const float* xb = x + (size_t)b*96*NPX + px;
    u16* orow = xt + ((size_t)b*NPX + px)*96;
    #pragma unroll 3
    for (int cg = 0; cg < 12; ++cg) {
        float v[8];
        #pragma unroll
        for (int j = 0; j < 8; ++j) v[j] = xb[(size_t)(cg*8 + j) * NPX];
        uint4 o;
        o.x = pk2bf(v[0], v[1]); o.y = pk2bf(v[2], v[3]);
        o.z = pk2bf(v[4], v[5]); o.w = pk2bf(v[6], v[7]);
        *(uint4*)(orow + cg*8) = o;
    }
}

// ---------------------------------------------------------------- conv weight pre-pack
// Bfrag[(ck*9+tap)*6+nt][lane][j] = bf16( w[nt*16+(lane&15)][ck*32+(lane>>4)*8+j][dy][dx] )
__global__ __launch_bounds__(64) void k_wprep(
    const float* __restrict__ cw, u16* __restrict__ Bfrag)
{
    int ks   = blockIdx.x;        // 0..161 = (ck*9+tap)*6+nt
    int lane = threadIdx.x;
    int nt    = ks % 6;
    int kstep = ks / 6;
    int tap   = kstep % 9;
    int ck    = kstep / 9;
    int dy = tap / 3, dx = tap % 3;
    int cout = nt*16 + (lane & 15);
    int cin0 = ck*32 + (lane >> 4)*8;
    u16* dst = Bfrag + (size_t)ks*512 + lane*8;
    #pragma unroll
    for (int j = 0; j < 8; ++j)
        dst[j] = f2bf(cw[((size_t)(cout*96 + cin0 + j))*9 + dy*3 + dx]);
}

// ---------------------------------------------------------------- QKV weight pre-pack
// BfragQ[kstep*18+nt][lane][j] = bf16( W[nt*16+(lane&15)][kstep*32+(lane>>4)*8+j] )
// W = concat(QK_w rows 0..191, V_w rows 0..95)
__global__ __launch_bounds__(64) void k_wprep_qkv(
    const float* __restrict__ qkw, const float* __restrict__ vw,
    u16* __restrict__ BfragQ)
{
    int ks   = blockIdx.x;        // 0..53 = kstep*18 + nt
    int lane = threadIdx.x;
    int nt    = ks % 18;
    int kstep = ks / 18;
    int o     = nt*16 + (lane & 15);
    int cin0  = kstep*32 + (lane >> 4)*8;
    const float* src = (o < 192) ? (qkw + (size_t)o*96 + cin0)
                                 : (vw + (size_t)(o - 192)*96 + cin0);
    u16* dst = BfragQ + (size_t)ks*512 + lane*8;
    #pragma unroll
    for (int j = 0; j < 8; ++j) dst[j] = f2bf(src[j]);
}

// ---------------------------------------------------------------- QKV 1x1 conv (MFMA)
// block: 256 px x 96 outs (og selects QK0/QK1/V). No LDS, no barriers.
// out: qkv[b*px][288] bf16: 0..191 = QK, 192..287 = V
__global__ __launch_bounds__(256, 2) void k_qkv(
    const u16* __restrict__ xt, const u16* __restrict__ BfragQ,
    const float* __restrict__ qkb, const float* __restrict__ vb,
    u16* __restrict__ qkv)
{
    int og   = blockIdx.x;                 // 0..2
    int tile = blockIdx.y;                 // 0..2047
    size_t px0 = (size_t)tile * 256;
    int t    = threadIdx.x;
    int wv   = __builtin_amdgcn_readfirstlane(t >> 6);
    int lane = t & 63;
    int lc   = lane & 15;
    int kg   = lane >> 4;

    f32x4 acc[4][6] = {};
    const u16* arow = xt + (px0 + wv*64 + lc)*96 + kg*8;
    const u16* bbase = BfragQ + (size_t)(og*6)*512 + lane*8;

    #pragma unroll
    for (int kstep = 0; kstep < 3; ++kstep) {
        bf16x8 bF[6];
        #pragma unroll
        for (int nt = 0; nt < 6; ++nt)
            bF[nt] = *(const bf16x8*)(bbase + (size_t)(kstep*18 + nt)*512);
        #pragma unroll
        for (int mt = 0; mt < 4; ++mt) {
            bf16x8 aF = *(const bf16x8*)(arow + (size_t)mt*16*96 + kstep*32);
            #pragma unroll
            for (int nt = 0; nt < 6; ++nt)
                acc[mt][nt] = __builtin_amdgcn_mfma_f32_16x16x32_bf16(aF, bF[nt], acc[mt][nt], 0, 0, 0);
        }
    }

    float bv[6];
    #pragma unroll
    for (int nt = 0; nt < 6; ++nt) {
        int o = og*96 + nt*16 + lc;
        bv[nt] = (o < 192) ? qkb[o] : vb[o - 192];
    }

    #pragma unroll
    for (int mt = 0; mt < 4; ++mt) {
        #pragma unroll
        for (int r = 0; r < 4; ++r) {
            size_t px = px0 + wv*64 + mt*16 + kg*4 + r;
            u16* qp = qkv + px*288 + og*96 + lc;
            #pragma unroll
            for (int nt = 0; nt < 6; ++nt)
                qp[nt*16] = f2bf(acc[mt][nt][r] + bv[nt]);
        }
    }
}

// ---------------------------------------------------------------- window attention
// one wave per (window, head); online softmax with defer-rescale (THR=8).
// att output: pixel-major [b][y][x][96] bf16
__global__ __launch_bounds__(64, 4) void k_attn(
    const u16* __restrict__ qkv, const float* __restrict__ biasT,
    u16* __restrict__ att)
{
    int win = blockIdx.x;               // 0..8711
    int h   = blockIdx.y;               // 0..2 (scalar)
    int b   = win / 1089;
    int wr  = win - b * 1089;
    int wy  = wr / NWIN;
    int wx  = wr - wy * NWIN;
    int n   = threadIdx.x;              // 0..63 query index

    int py = wy*8 + (n >> 3) - 4;       // original coords (pre-reflect)
    int px = wx*8 + (n & 7)  - 4;
    int iy = refl(py, IMG), ix = refl(px, IMG);

    // q row -> f32 regs (lane-varying load)
    float q[32];
    {
        const uint4* qp = (const uint4*)(qkv + ((size_t)(b*NPX + iy*256 + ix))*288 + h*32);
        #pragma unroll
        for (int w4 = 0; w4 < 4; ++w4) {
            uint4 v = qp[w4];
            u32 qu[4] = {v.x, v.y, v.z, v.w};
            #pragma unroll
            for (int dd = 0; dd < 4; ++dd) {
                q[w4*8 + 2*dd]     = bflo(qu[dd]);
                q[w4*8 + 2*dd + 1] = bfhi(qu[dd]);
            }
        }
    }

    float o_[32] = {};
    float mx = -1e30f, sum = 0.0f;
    const float* bp = biasT + h*4096 + n;      // + m*64 per step

    #pragma unroll 2
    for (int m = 0; m < 64; ++m) {
        int my  = refl(wy*8 + (m >> 3) - 4, IMG);    // uniform
        int mxx = refl(wx*8 + (m & 7)  - 4, IMG);    // uniform
        const u16* krow = qkv + ((size_t)(b*NPX + my*256 + mxx))*288 + 96 + h*32;

        // s = q . k  (K row is wave-uniform -> scalar loads)
        float ap0 = 0.f, ap1 = 0.f, ap2 = 0.f, ap3 = 0.f;
        #pragma unroll
        for (int w4 = 0; w4 < 4; ++w4) {
            uint4 v = ((const uint4*)krow)[w4];
            u32 ku[4] = {v.x, v.y, v.z, v.w};
            #pragma unroll
            for (int dd = 0; dd < 4; ++dd) {
                float kl = bflo(ku[dd]), kh = bfhi(ku[dd]);
                ap0 = fmaf(q[w4*8 + 2*dd],     kl, ap0);
                ap1 = fmaf(q[w4*8 + 2*dd + 1], kh, ap1);
            }
            float t2 = ap2; ap2 = ap3; ap3 = t2;   // rotate to spread deps
        }
        float s = fmaf((ap0 + ap1) + (ap2 + ap3), ATT_SCALE, bp[m*64]);

        // online softmax, defer-rescale
        float p;
        if (s <= mx + 8.0f) {
            p = __expf(s - mx);
        } else {
            float r = __expf(mx - s);
            sum *= r;
            #pragma unroll
            for (int d = 0; d < 32; ++d) o_[d] *= r;
            mx = s;
            p = 1.0f;
        }
        sum += p;

        // o_ += p * v   (V row wave-uniform)
        const u16* vrow = krow + 96;
        #pragma unroll
        for (int w4 = 0; w4 < 4; ++w4) {
            uint4 v = ((const uint4*)vrow)[w4];
            u32 vu[4] = {v.x, v.y, v.z, v.w};
            #pragma unroll
            for (int dd = 0; dd < 4; ++dd) {
                o_[w4*8 + 2*dd]     = fmaf(p, bflo(vu[dd]), o_[w4*8 + 2*dd]);
                o_[w4*8 + 2*dd + 1] = fmaf(p, bfhi(vu[dd]), o_[w4*8 + 2*dd + 1]);
            }
        }
    }

    if (py >= 0 && py < IMG && px >= 0 && px < IMG) {
        float inv = 1.0f / sum;
        u16* op = att + ((size_t)(b*NPX + py*256 + px))*96 + h*32;
        #pragma unroll
        for (int o4 = 0; o4 < 8; ++o4) {
            ushort4 sv;
            sv.x = f2bf(o_[o4*4+0] * inv); sv.y = f2bf(o_[o4*4+1] * inv);
            sv.z = f2bf(o_[o4*4+2] * inv); sv.w = f2bf(o_[o4*4+3] * inv);
            *(ushort4*)(op + o4*4) = sv;
        }
    }
}

// ---------------------------------------------------------------- 3x3 conv + attn add (MFMA)
// block: 8x32 px output tile, 96 cout. LDS: 10x34 halo x 96ch bf16, 208B pitch.
// K = 3 cin-chunks x 9 taps x K32. Wave w: rows {2w,2w+1}, acc 4mt x 6nt.
__global__ __launch_bounds__(256, 2) void k_conv(
    const u16* __restrict__ qkv, const u16* __restrict__ att,
    const u16* __restrict__ Bfrag, const float* __restrict__ cb,
    u16* __restrict__ S)
{
    int tile = blockIdx.x;              // 0..2047
    int b    = tile >> 8;
    int tr   = tile & 255;              // 32 row-tiles x 8 col-tiles
    int ty0  = (tr >> 3) * 8;
    int tx0  = (tr & 7) * 32;
    int t    = threadIdx.x;

    __shared__ u16 vt[340 * HALO_PITCH];   // 70,720 B

    // stage halo (10x34 px, 96 ch each) -> LDS, bf16
    for (int p = t; p < 340; p += 256) {
        int hr = p / 34;
        int hc = p - hr * 34;
        int gy = refl(ty0 - 1 + hr, IMG);
        int gx = refl(tx0 - 1 + hc, IMG);
        const uint4* src = (const uint4*)(qkv + ((size_t)(b*NPX + gy*256 + gx))*288 + 192);
        uint4* dst = (uint4*)(vt + p * HALO_PITCH);
        #pragma unroll
        for (int q = 0; q < 12; ++q) dst[q] = src[q];
    }
    __syncthreads();

    int wv   = __builtin_amdgcn_readfirstlane(t >> 6);
    int lane = t & 63;
    int lc   = lane & 15;
    int kg   = lane >> 4;

    int abase[4];
    #pragma unroll
    for (int mt = 0; mt < 4; ++mt) {
        int r_mt = 2*wv + (mt >> 1);
        int c_mt = (mt & 1) * 16;
        abase[mt] = (r_mt*34 + c_mt + lc) * HALO_PITCH + kg*8;
    }

    f32x4 acc[4][6] = {};

    const u16* bfr = Bfrag + lane*8;
    #pragma unroll 1
    for (int ck = 0; ck < 3; ++ck) {
        const u16* bck = bfr + ck * 27648;     // ck * 9 taps * 6 nt * 512
        int aoff = ck * 32;
        #pragma unroll
        for (int tap = 0; tap < 9; ++tap) {
            const int dy = tap / 3, dx = tap % 3;
            bf16x8 bF[6];
            #pragma unroll
            for (int nt = 0; nt < 6; ++nt)
                bF[nt] = *(const bf16x8*)(bck + (tap*6 + nt)*512);
            #pragma unroll
            for (int mt = 0; mt < 4; ++mt) {
                bf16x8 aF = *(const bf16x8*)(vt + abase[mt] + aoff + (dy*34 + dx)*HALO_PITCH);
                #pragma unroll
                for (int nt = 0; nt < 6; ++nt)
                    acc[mt][nt] = __builtin_amdgcn_mfma_f32_16x16x32_bf16(aF, bF[nt], acc[mt][nt], 0, 0, 0);
            }
        }
    }

    // epilogue: + conv bias + attn, store bf16 pixel-major
    float cbv[6];
    #pragma unroll
    for (int nt = 0; nt < 6; ++nt) cbv[nt] = cb[nt*16 + lc];

    #pragma unroll
    for (int mt = 0; mt < 4; ++mt) {
        int r_mt = 2*wv + (mt >> 1);
        int c_mt = (mt & 1) * 16;
        int y    = ty0 + r_mt;
        #pragma unroll
        for (int r = 0; r < 4; ++r) {
            int x = tx0 + c_mt + kg*4 + r;          // C row = kg*4 + r -> pixel within mtile
            size_t pbase = ((size_t)(b*NPX + y*256 + x))*96 + lc;
            #pragma unroll
            for (int nt = 0; nt < 6; ++nt) {
                float v = acc[mt][nt][r] + cbv[nt] + bf2f(att[pbase + nt*16]);
                S[pbase + nt*16] = f2bf(v);
            }
        }
    }
}

// ---------------------------------------------------------------- proj 1x1 conv
__global__ __launch_bounds__(256, 2) void k_proj(
    const u16* __restrict__ S,
    const float* __restrict__ pw, const float* __restrict__ pb,
    float* __restrict__ out)
{
    int tile = blockIdx.x;
    int b    = tile >> 8;
    int pix0 = (tile & 255) * 256;
    int t    = threadIdx.x;
    int oslice = __builtin_amdgcn_readfirstlane(t >> 6);
    int pxg  = t & 63;
    int px   = pix0 + pxg * 4;

    float acc[24][4] = {};
    const u16* srow = S + ((size_t)(b*NPX + px)) * 96;

    for (int cc = 0; cc < 12; ++cc) {
        float xr[8][4];
        #pragma unroll
        for (int j = 0; j < 4; ++j) {
            uint4 v = *(const uint4*)(srow + (size_t)j * 96 + cc*8);
            u32 su[4] = {v.x, v.y, v.z, v.w};
            #pragma unroll
            for (int dd = 0; dd < 4; ++dd) {
                xr[2*dd][j]   = bflo(su[dd]);
                xr[2*dd+1][j] = bfhi(su[dd]);
            }
        }
        #pragma unroll
        for (int o = 0; o < 24; ++o) {
            const float* wr = pw + (oslice*24 + o) * 96 + cc*8;
            #pragma unroll
            for (int c = 0; c < 8; ++c) {
                float w = wr[c];
                #pragma unroll
                for (int j = 0; j < 4; ++j)
                    acc[o][j] = fmaf(w, xr[c][j], acc[o][j]);
            }
        }
    }
    #pragma unroll
    for (int o = 0; o < 24; ++o) {
        int oc = oslice*24 + o;
        float bv = pb[oc];
        float4 v;
        v.x = acc[o][0] + bv; v.y = acc[o][1] + bv;
        v.z = acc[o][2] + bv; v.w = acc[o][3] + bv;
        *(float4*)(out + (size_t)(b*96 + oc) * NPX + px) = v;
    }
}

// ----------------------------------------------------------------
extern "C" void kernel_launch(void* const* d_in, const int* in_sizes, int n_in,
                              void* d_out, int out_size, void* d_ws, size_t ws_size,
                              hipStream_t stream)
{
    const float* x      = (const float*)d_in[0];
    const float* V_w    = (const float*)d_in[1];
    const float* V_b    = (const float*)d_in[2];
    const float* QK_w   = (const float*)d_in[3];
    const float* QK_b   = (const float*)d_in[4];
    const float* conv_w = (const float*)d_in[5];
    const float* conv_b = (const float*)d_in[6];
    const float* proj_w = (const float*)d_in[7];
    const float* proj_b = (const float*)d_in[8];
    const float* m1_w   = (const float*)d_in[9];
    const float* m1_b   = (const float*)d_in[10];
    const float* m2_w   = (const float*)d_in[11];
    const float* m2_b   = (const float*)d_in[12];
    float* out = (float*)d_out;

    char* ws = (char*)d_ws;
    float* biasT = (float*)ws;                                      // 49152 B
    u16* qkvb = (u16*)(ws + 49152);                                 // 301989888 B
    u16* attb = (u16*)(ws + 49152 + 301989888);                     // 100663296 B
    u16* sbuf = (u16*)(ws + 49152 + 301989888 + 100663296);         // 100663296 B

    // scratch carved from d_out (consumed before k_proj writes it):
    //   [0, 332K)   conv-weight B-fragments
    //   [1M, 1.06M) qkv-weight B-fragments
    //   [2M, 103M)  x_t : x transposed to pixel-major bf16
    char* ob = (char*)d_out;
    u16* Bfrag  = (u16*)ob;
    u16* BfragQ = (u16*)(ob + (1 << 20));
    u16* xtb    = (u16*)(ob + (2 << 20));

    hipLaunchKernelGGL(k_wprep,     dim3(162),     dim3(64),  0, stream, conv_w, Bfrag);
    hipLaunchKernelGGL(k_wprep_qkv, dim3(54),      dim3(64),  0, stream, QK_w, V_w, BfragQ);
    hipLaunchKernelGGL(k_bias,      dim3(48),      dim3(256), 0, stream, m1_w, m1_b, m2_w, m2_b, biasT);
    hipLaunchKernelGGL(k_xt,        dim3(2048),    dim3(256), 0, stream, x, xtb);
    hipLaunchKernelGGL(k_qkv,       dim3(3, 2048), dim3(256), 0, stream, xtb, BfragQ, QK_b, V_b, qkvb);
    hipLaunchKernelGGL(k_attn,      dim3(8712, 3), dim3(64),  0, stream, qkvb, biasT, attb);
    hipLaunchKernelGGL(k_conv,      dim3(2048),    dim3(256), 0, stream, qkvb, attb, Bfrag, conv_b, sbuf);
    hipLaunchKernelGGL(k_proj,      dim3(2048),    dim3(256), 0, stream, sbuf, proj_w, proj_b, out);
}

// Round 5
// 835.282 us; speedup vs baseline: 6.0143x; 1.2739x over previous
//
#include <hip/hip_runtime.h>
#include <cstdint>

using u16 = unsigned short;
using u32 = unsigned int;
using f32x4  = __attribute__((ext_vector_type(4))) float;
using bf16x8 = __attribute__((ext_vector_type(8))) short;

#define NHEADS 3
#define WSZ 8
#define IMG 256
#define NPX 65536          // pixels per image
#define NWIN 33            // windows per side
#define ATT_SCALE 0.17677669529663687f
#define INV_SCALE 5.656854249492381f
#define HALO_PITCH 104     // u16 per halo pixel (208 B: 96 ch + 8 pad -> conflict-free)

__device__ __forceinline__ int refl(int i, int n) {
    return i < 0 ? -i : (i >= n ? 2*n - 2 - i : i);
}
__device__ __forceinline__ float bflo(u32 u){ union{u32 i; float f;} x; x.i = u << 16; return x.f; }
__device__ __forceinline__ float bfhi(u32 u){ union{u32 i; float f;} x; x.i = u & 0xffff0000u; return x.f; }
__device__ __forceinline__ float bf2f(u16 v){ union{u32 i; float f;} x; x.i = ((u32)v) << 16; return x.f; }
__device__ __forceinline__ u16 f2bf(float f){
    union{float f; u32 i;} x; x.f = f;
    u32 r = x.i + 0x7fffu + ((x.i >> 16) & 1u);
    return (u16)(r >> 16);
}
__device__ __forceinline__ u32 pk2bf(float a, float b){
    return (u32)f2bf(a) | ((u32)f2bf(b) << 16);
}

// ---------------------------------------------------------------- bias table
// biasS[h][q][key] = bias[h][q][key] / ATT_SCALE   (scale folded into exp arg)
__global__ __launch_bounds__(256) void k_bias(
    const float* __restrict__ m1w, const float* __restrict__ m1b,
    const float* __restrict__ m2w, const float* __restrict__ m2b,
    float* __restrict__ biasS)
{
    int idx = blockIdx.x * 256 + threadIdx.x;   // 0..12287
    int hh  = idx >> 12;
    int rem = idx & 4095;
    int n = rem >> 6, m = rem & 63;             // n = query, m = key
    int di = (n >> 3) - (m >> 3);
    int dj = (n & 7)  - (m & 7);
    float fdi = copysignf(log1pf(fabsf((float)di)), (float)di);
    float fdj = copysignf(log1pf(fabsf((float)dj)), (float)dj);
    float acc = m2b[hh];
    for (int k = 0; k < 256; ++k) {
        float tv = fdi * m1w[2*k] + fdj * m1w[2*k+1] + m1b[k];
        float g  = 0.5f * tv * (1.0f + erff(tv * 0.70710678118654752f));
        acc = fmaf(g, m2w[hh*256 + k], acc);
    }
    biasS[hh*4096 + n*64 + m] = acc * INV_SCALE;
}

// ---------------------------------------------------------------- x transpose: [b][c][px] f32 -> [b*px][96] bf16
__global__ __launch_bounds__(256, 4) void k_xt(
    const float* __restrict__ x, u16* __restrict__ xt)
{
    int blk = blockIdx.x;            // 0..2047
    int b   = blk >> 8;
    int pt  = blk & 255;
    int px  = pt*256 + threadIdx.x;
    const float* xb = x + (size_t)b*96*NPX + px;
    u16* orow = xt + ((size_t)b*NPX + px)*96;
    #pragma unroll 3
    for (int cg = 0; cg < 12; ++cg) {
        float v[8];
        #pragma unroll
        for (int j = 0; j < 8; ++j) v[j] = xb[(size_t)(cg*8 + j) * NPX];
        uint4 o;
        o.x = pk2bf(v[0], v[1]); o.y = pk2bf(v[2], v[3]);
        o.z = pk2bf(v[4], v[5]); o.w = pk2bf(v[6], v[7]);
        *(uint4*)(orow + cg*8) = o;
    }
}

// ---------------------------------------------------------------- conv weight pre-pack
__global__ __launch_bounds__(64) void k_wprep(
    const float* __restrict__ cw, u16* __restrict__ Bfrag)
{
    int ks   = blockIdx.x;        // 0..161 = (ck*9+tap)*6+nt
    int lane = threadIdx.x;
    int nt    = ks % 6;
    int kstep = ks / 6;
    int tap   = kstep % 9;
    int ck    = kstep / 9;
    int dy = tap / 3, dx = tap % 3;
    int cout = nt*16 + (lane & 15);
    int cin0 = ck*32 + (lane >> 4)*8;
    u16* dst = Bfrag + (size_t)ks*512 + lane*8;
    #pragma unroll
    for (int j = 0; j < 8; ++j)
        dst[j] = f2bf(cw[((size_t)(cout*96 + cin0 + j))*9 + dy*3 + dx]);
}

// ---------------------------------------------------------------- QKV weight pre-pack
__global__ __launch_bounds__(64) void k_wprep_qkv(
    const float* __restrict__ qkw, const float* __restrict__ vw,
    u16* __restrict__ BfragQ)
{
    int ks   = blockIdx.x;        // 0..53 = kstep*18 + nt
    int lane = threadIdx.x;
    int nt    = ks % 18;
    int kstep = ks / 18;
    int o     = nt*16 + (lane & 15);
    int cin0  = kstep*32 + (lane >> 4)*8;
    const float* src = (o < 192) ? (qkw + (size_t)o*96 + cin0)
                                 : (vw + (size_t)(o - 192)*96 + cin0);
    u16* dst = BfragQ + (size_t)ks*512 + lane*8;
    #pragma unroll
    for (int j = 0; j < 8; ++j) dst[j] = f2bf(src[j]);
}

// ---------------------------------------------------------------- QKV 1x1 conv (MFMA)
__global__ __launch_bounds__(256, 2) void k_qkv(
    const u16* __restrict__ xt, const u16* __restrict__ BfragQ,
    const float* __restrict__ qkb, const float* __restrict__ vb,
    u16* __restrict__ qkv)
{
    int og   = blockIdx.x;                 // 0..2
    int tile = blockIdx.y;                 // 0..2047
    size_t px0 = (size_t)tile * 256;
    int t    = threadIdx.x;
    int wv   = __builtin_amdgcn_readfirstlane(t >> 6);
    int lane = t & 63;
    int lc   = lane & 15;
    int kg   = lane >> 4;

    f32x4 acc[4][6] = {};
    const u16* arow = xt + (px0 + wv*64 + lc)*96 + kg*8;
    const u16* bbase = BfragQ + (size_t)(og*6)*512 + lane*8;

    #pragma unroll
    for (int kstep = 0; kstep < 3; ++kstep) {
        bf16x8 bF[6];
        #pragma unroll
        for (int nt = 0; nt < 6; ++nt)
            bF[nt] = *(const bf16x8*)(bbase + (size_t)(kstep*18 + nt)*512);
        #pragma unroll
        for (int mt = 0; mt < 4; ++mt) {
            bf16x8 aF = *(const bf16x8*)(arow + (size_t)mt*16*96 + kstep*32);
            #pragma unroll
            for (int nt = 0; nt < 6; ++nt)
                acc[mt][nt] = __builtin_amdgcn_mfma_f32_16x16x32_bf16(aF, bF[nt], acc[mt][nt], 0, 0, 0);
        }
    }

    float bv[6];
    #pragma unroll
    for (int nt = 0; nt < 6; ++nt) {
        int o = og*96 + nt*16 + lc;
        bv[nt] = (o < 192) ? qkb[o] : vb[o - 192];
    }

    #pragma unroll
    for (int mt = 0; mt < 4; ++mt) {
        #pragma unroll
        for (int r = 0; r < 4; ++r) {
            size_t px = px0 + wv*64 + mt*16 + kg*4 + r;
            u16* qp = qkv + px*288 + og*96 + lc;
            #pragma unroll
            for (int nt = 0; nt < 6; ++nt)
                qp[nt*16] = f2bf(acc[mt][nt][r] + bv[nt]);
        }
    }
}

// ---------------------------------------------------------------- window attention (MFMA)
// 1 wave per window, 4 waves/block. Swapped QK^T: D[key][q] = mfma(K, Q, bias/scale).
// Softmax over (mt,reg) in-lane + shfl_xor(16,32). P normalized, bf16 -> LDS [64][72],
// V transposed -> LDS [32][72]. PV: D[q][c] = mfma(P, Vt). No barriers (intra-wave).
__global__ __launch_bounds__(256, 2) void k_attn(
    const u16* __restrict__ qkv, const float* __restrict__ biasS,
    u16* __restrict__ att)
{
    __shared__ u16 lds[27648];           // 4 waves x (P 64x72 + Vt 32x72)
    int t    = threadIdx.x;
    int wv   = __builtin_amdgcn_readfirstlane(t >> 6);
    int lane = t & 63;
    int lc   = lane & 15;
    int kg   = lane >> 4;

    u16* Plds = lds + wv * 6912;         // [64][72] bf16
    u16* Vlds = Plds + 4608;             // [32][72] bf16

    int win = blockIdx.x * 4 + wv;       // 0..8711
    int b   = win / 1089;
    int wr  = win - b * 1089;
    int wy  = wr / NWIN;
    int wx  = wr - wy * NWIN;

    // pixel table: lane holds window pixel n = lane (sign bit = invalid for store)
    int py = wy*8 + (lane >> 3) - 4;
    int px = wx*8 + (lane & 7)  - 4;
    int iy = refl(py, IMG), ix = refl(px, IMG);
    int pxoff = b*NPX + iy*256 + ix;
    int vpx = (py >= 0 && py < IMG && px >= 0 && px < IMG) ? pxoff : (int)(pxoff | 0x80000000u);

    // Q/K row pixels for fragment loads: n = 16*mt + lc
    int pxA[4];
    #pragma unroll
    for (int mt = 0; mt < 4; ++mt)
        pxA[mt] = __builtin_amdgcn_ds_bpermute((16*mt + lc)*4, vpx) & 0x7fffffff;

    #pragma unroll 1
    for (int h = 0; h < 3; ++h) {
        // V rows -> Vt LDS (transposed): Vt[c][key], key = lane
        {
            const u16* vrow = qkv + (size_t)pxoff*288 + 192 + h*32;
            #pragma unroll
            for (int g = 0; g < 4; ++g) {
                bf16x8 vv = *(const bf16x8*)(vrow + g*8);
                #pragma unroll
                for (int j = 0; j < 8; ++j)
                    Vlds[(g*8 + j)*72 + lane] = (u16)vv[j];
            }
        }

        // K (A-side) / Q (B-side) fragments
        bf16x8 afr[4], bfr[4];
        #pragma unroll
        for (int mt = 0; mt < 4; ++mt) {
            afr[mt] = *(const bf16x8*)(qkv + (size_t)pxA[mt]*288 + 96 + h*32 + kg*8);
            bfr[mt] = *(const bf16x8*)(qkv + (size_t)pxA[mt]*288 +      h*32 + kg*8);
        }

        // acc init = bias/scale at [key=16mt+4kg+r][q=16nt+lc]
        f32x4 acc[4][4];
        const float* bb = biasS + h*4096 + lc*64 + 4*kg;
        #pragma unroll
        for (int nt = 0; nt < 4; ++nt)
            #pragma unroll
            for (int mt = 0; mt < 4; ++mt)
                acc[mt][nt] = *(const f32x4*)(bb + nt*1024 + mt*16);

        #pragma unroll
        for (int mt = 0; mt < 4; ++mt)
            #pragma unroll
            for (int nt = 0; nt < 4; ++nt)
                acc[mt][nt] = __builtin_amdgcn_mfma_f32_16x16x32_bf16(afr[mt], bfr[nt], acc[mt][nt], 0, 0, 0);

        // softmax over keys for each q (= col): in-lane 16 + cross-kg shuffles
        #pragma unroll
        for (int nt = 0; nt < 4; ++nt) {
            float m = acc[0][nt][0];
            #pragma unroll
            for (int mt = 0; mt < 4; ++mt)
                #pragma unroll
                for (int r = 0; r < 4; ++r)
                    m = fmaxf(m, acc[mt][nt][r]);
            m = fmaxf(m, __shfl_xor(m, 16));
            m = fmaxf(m, __shfl_xor(m, 32));
            float s = 0.f;
            #pragma unroll
            for (int mt = 0; mt < 4; ++mt)
                #pragma unroll
                for (int r = 0; r < 4; ++r) {
                    float p = __expf((acc[mt][nt][r] - m) * ATT_SCALE);
                    acc[mt][nt][r] = p;
                    s += p;
                }
            s += __shfl_xor(s, 16);
            s += __shfl_xor(s, 32);
            float inv = 1.0f / s;
            #pragma unroll
            for (int mt = 0; mt < 4; ++mt)
                #pragma unroll
                for (int r = 0; r < 4; ++r)
                    acc[mt][nt][r] *= inv;
        }

        // P -> LDS: P[q=16nt+lc][key=16mt+4kg+(0..3)], stride 72
        #pragma unroll
        for (int nt = 0; nt < 4; ++nt)
            #pragma unroll
            for (int mt = 0; mt < 4; ++mt) {
                uint2 pk;
                pk.x = pk2bf(acc[mt][nt][0], acc[mt][nt][1]);
                pk.y = pk2bf(acc[mt][nt][2], acc[mt][nt][3]);
                *(uint2*)(Plds + (16*nt + lc)*72 + 16*mt + 4*kg) = pk;
            }

        // PV: D[q][c] = sum_key P[q][key] * V[key][c]
        f32x4 oacc[4][2] = {};
        #pragma unroll
        for (int s = 0; s < 2; ++s) {
            bf16x8 vb2[2];
            #pragma unroll
            for (int ntpv = 0; ntpv < 2; ++ntpv)
                vb2[ntpv] = *(const bf16x8*)(Vlds + (16*ntpv + lc)*72 + s*32 + kg*8);
            #pragma unroll
            for (int mtpv = 0; mtpv < 4; ++mtpv) {
                bf16x8 pa = *(const bf16x8*)(Plds + (16*mtpv + lc)*72 + s*32 + kg*8);
                #pragma unroll
                for (int ntpv = 0; ntpv < 2; ++ntpv)
                    oacc[mtpv][ntpv] = __builtin_amdgcn_mfma_f32_16x16x32_bf16(pa, vb2[ntpv], oacc[mtpv][ntpv], 0, 0, 0);
            }
        }

        // store: out[q = 16mtpv+4kg+rr][c = 16ntpv+lc] -> att[px(q)][h*32 + c]
        #pragma unroll
        for (int mtpv = 0; mtpv < 4; ++mtpv)
            #pragma unroll
            for (int rr = 0; rr < 4; ++rr) {
                int vp = __builtin_amdgcn_ds_bpermute((16*mtpv + 4*kg + rr)*4, vpx);
                if (vp >= 0) {
                    u16* op = att + (size_t)vp*96 + h*32 + lc;
                    op[0]  = f2bf(oacc[mtpv][0][rr]);
                    op[16] = f2bf(oacc[mtpv][1][rr]);
                }
            }
    }
}

// ---------------------------------------------------------------- 3x3 conv + attn add (MFMA)
__global__ __launch_bounds__(256, 2) void k_conv(
    const u16* __restrict__ qkv, const u16* __restrict__ att,
    const u16* __restrict__ Bfrag, const float* __restrict__ cb,
    u16* __restrict__ S)
{
    int tile = blockIdx.x;              // 0..2047
    int b    = tile >> 8;
    int tr   = tile & 255;              // 32 row-tiles x 8 col-tiles
    int ty0  = (tr >> 3) * 8;
    int tx0  = (tr & 7) * 32;
    int t    = threadIdx.x;

    __shared__ u16 vt[340 * HALO_PITCH];   // 70,720 B

    for (int p = t; p < 340; p += 256) {
        int hr = p / 34;
        int hc = p - hr * 34;
        int gy = refl(ty0 - 1 + hr, IMG);
        int gx = refl(tx0 - 1 + hc, IMG);
        const uint4* src = (const uint4*)(qkv + ((size_t)(b*NPX + gy*256 + gx))*288 + 192);
        uint4* dst = (uint4*)(vt + p * HALO_PITCH);
        #pragma unroll
        for (int q = 0; q < 12; ++q) dst[q] = src[q];
    }
    __syncthreads();

    int wv   = __builtin_amdgcn_readfirstlane(t >> 6);
    int lane = t & 63;
    int lc   = lane & 15;
    int kg   = lane >> 4;

    int abase[4];
    #pragma unroll
    for (int mt = 0; mt < 4; ++mt) {
        int r_mt = 2*wv + (mt >> 1);
        int c_mt = (mt & 1) * 16;
        abase[mt] = (r_mt*34 + c_mt + lc) * HALO_PITCH + kg*8;
    }

    f32x4 acc[4][6] = {};

    const u16* bfr = Bfrag + lane*8;
    #pragma unroll 1
    for (int ck = 0; ck < 3; ++ck) {
        const u16* bck = bfr + ck * 27648;
        int aoff = ck * 32;
        #pragma unroll
        for (int tap = 0; tap < 9; ++tap) {
            const int dy = tap / 3, dx = tap % 3;
            bf16x8 bF[6];
            #pragma unroll
            for (int nt = 0; nt < 6; ++nt)
                bF[nt] = *(const bf16x8*)(bck + (tap*6 + nt)*512);
            #pragma unroll
            for (int mt = 0; mt < 4; ++mt) {
                bf16x8 aF = *(const bf16x8*)(vt + abase[mt] + aoff + (dy*34 + dx)*HALO_PITCH);
                #pragma unroll
                for (int nt = 0; nt < 6; ++nt)
                    acc[mt][nt] = __builtin_amdgcn_mfma_f32_16x16x32_bf16(aF, bF[nt], acc[mt][nt], 0, 0, 0);
            }
        }
    }

    float cbv[6];
    #pragma unroll
    for (int nt = 0; nt < 6; ++nt) cbv[nt] = cb[nt*16 + lc];

    #pragma unroll
    for (int mt = 0; mt < 4; ++mt) {
        int r_mt = 2*wv + (mt >> 1);
        int c_mt = (mt & 1) * 16;
        int y    = ty0 + r_mt;
        #pragma unroll
        for (int r = 0; r < 4; ++r) {
            int x = tx0 + c_mt + kg*4 + r;
            size_t pbase = ((size_t)(b*NPX + y*256 + x))*96 + lc;
            #pragma unroll
            for (int nt = 0; nt < 6; ++nt) {
                float v = acc[mt][nt][r] + cbv[nt] + bf2f(att[pbase + nt*16]);
                S[pbase + nt*16] = f2bf(v);
            }
        }
    }
}

// ---------------------------------------------------------------- proj 1x1 conv
__global__ __launch_bounds__(256, 2) void k_proj(
    const u16* __restrict__ S,
    const float* __restrict__ pw, const float* __restrict__ pb,
    float* __restrict__ out)
{
    int tile = blockIdx.x;
    int b    = tile >> 8;
    int pix0 = (tile & 255) * 256;
    int t    = threadIdx.x;
    int oslice = __builtin_amdgcn_readfirstlane(t >> 6);
    int pxg  = t & 63;
    int px   = pix0 + pxg * 4;

    float acc[24][4] = {};
    const u16* srow = S + ((size_t)(b*NPX + px)) * 96;

    for (int cc = 0; cc < 12; ++cc) {
        float xr[8][4];
        #pragma unroll
        for (int j = 0; j < 4; ++j) {
            uint4 v = *(const uint4*)(srow + (size_t)j * 96 + cc*8);
            u32 su[4] = {v.x, v.y, v.z, v.w};
            #pragma unroll
            for (int dd = 0; dd < 4; ++dd) {
                xr[2*dd][j]   = bflo(su[dd]);
                xr[2*dd+1][j] = bfhi(su[dd]);
            }
        }
        #pragma unroll
        for (int o = 0; o < 24; ++o) {
            const float* wr = pw + (oslice*24 + o) * 96 + cc*8;
            #pragma unroll
            for (int c = 0; c < 8; ++c) {
                float w = wr[c];
                #pragma unroll
                for (int j = 0; j < 4; ++j)
                    acc[o][j] = fmaf(w, xr[c][j], acc[o][j]);
            }
        }
    }
    #pragma unroll
    for (int o = 0; o < 24; ++o) {
        int oc = oslice*24 + o;
        float bv = pb[oc];
        float4 v;
        v.x = acc[o][0] + bv; v.y = acc[o][1] + bv;
        v.z = acc[o][2] + bv; v.w = acc[o][3] + bv;
        *(float4*)(out + (size_t)(b*96 + oc) * NPX + px) = v;
    }
}

// ----------------------------------------------------------------
extern "C" void kernel_launch(void* const* d_in, const int* in_sizes, int n_in,
                              void* d_out, int out_size, void* d_ws, size_t ws_size,
                              hipStream_t stream)
{
    const float* x      = (const float*)d_in[0];
    const float* V_w    = (const float*)d_in[1];
    const float* V_b    = (const float*)d_in[2];
    const float* QK_w   = (const float*)d_in[3];
    const float* QK_b   = (const float*)d_in[4];
    const float* conv_w = (const float*)d_in[5];
    const float* conv_b = (const float*)d_in[6];
    const float* proj_w = (const float*)d_in[7];
    const float* proj_b = (const float*)d_in[8];
    const float* m1_w   = (const float*)d_in[9];
    const float* m1_b   = (const float*)d_in[10];
    const float* m2_w   = (const float*)d_in[11];
    const float* m2_b   = (const float*)d_in[12];
    float* out = (float*)d_out;

    char* ws = (char*)d_ws;
    float* biasS = (float*)ws;                                      // 49152 B
    u16* qkvb = (u16*)(ws + 49152);                                 // 301989888 B
    u16* attb = (u16*)(ws + 49152 + 301989888);                     // 100663296 B
    u16* sbuf = (u16*)(ws + 49152 + 301989888 + 100663296);         // 100663296 B

    // scratch carved from d_out (consumed before k_proj writes it)
    char* ob = (char*)d_out;
    u16* Bfrag  = (u16*)ob;
    u16* BfragQ = (u16*)(ob + (1 << 20));
    u16* xtb    = (u16*)(ob + (2 << 20));

    hipLaunchKernelGGL(k_wprep,     dim3(162),     dim3(64),  0, stream, conv_w, Bfrag);
    hipLaunchKernelGGL(k_wprep_qkv, dim3(54),      dim3(64),  0, stream, QK_w, V_w, BfragQ);
    hipLaunchKernelGGL(k_bias,      dim3(48),      dim3(256), 0, stream, m1_w, m1_b, m2_w, m2_b, biasS);
    hipLaunchKernelGGL(k_xt,        dim3(2048),    dim3(256), 0, stream, x, xtb);
    hipLaunchKernelGGL(k_qkv,       dim3(3, 2048), dim3(256), 0, stream, xtb, BfragQ, QK_b, V_b, qkvb);
    hipLaunchKernelGGL(k_attn,      dim3(2178),    dim3(256), 0, stream, qkvb, biasS, attb);
    hipLaunchKernelGGL(k_conv,      dim3(2048),    dim3(256), 0, stream, qkvb, attb, Bfrag, conv_b, sbuf);
    hipLaunchKernelGGL(k_proj,      dim3(2048),    dim3(256), 0, stream, sbuf, proj_w, proj_b, out);
}

// Round 6
// 591.691 us; speedup vs baseline: 8.4903x; 1.4117x over previous
//
#include <hip/hip_runtime.h>
#include <cstdint>

using u16 = unsigned short;
using u32 = unsigned int;
using f32x4  = __attribute__((ext_vector_type(4))) float;
using bf16x8 = __attribute__((ext_vector_type(8))) short;

#define NHEADS 3
#define WSZ 8
#define IMG 256
#define NPX 65536          // pixels per image
#define NWIN 33            // windows per side
#define ATT_SCALE 0.17677669529663687f
#define INV_SCALE 5.656854249492381f
#define HALO_PITCH 104     // u16 per halo pixel (208 B: 96 ch + 8 pad -> conflict-free)

__device__ __forceinline__ int refl(int i, int n) {
    return i < 0 ? -i : (i >= n ? 2*n - 2 - i : i);
}
__device__ __forceinline__ float bflo(u32 u){ union{u32 i; float f;} x; x.i = u << 16; return x.f; }
__device__ __forceinline__ float bfhi(u32 u){ union{u32 i; float f;} x; x.i = u & 0xffff0000u; return x.f; }
__device__ __forceinline__ float bf2f(u16 v){ union{u32 i; float f;} x; x.i = ((u32)v) << 16; return x.f; }
__device__ __forceinline__ u16 f2bf(float f){
    union{float f; u32 i;} x; x.f = f;
    u32 r = x.i + 0x7fffu + ((x.i >> 16) & 1u);
    return (u16)(r >> 16);
}
__device__ __forceinline__ u32 pk2bf(float a, float b){
    return (u32)f2bf(a) | ((u32)f2bf(b) << 16);
}

// ---------------------------------------------------------------- bias table
// biasS[h][q][key] = bias[h][q][key] / ATT_SCALE   (scale folded into exp arg)
__global__ __launch_bounds__(256) void k_bias(
    const float* __restrict__ m1w, const float* __restrict__ m1b,
    const float* __restrict__ m2w, const float* __restrict__ m2b,
    float* __restrict__ biasS)
{
    int idx = blockIdx.x * 256 + threadIdx.x;   // 0..12287
    int hh  = idx >> 12;
    int rem = idx & 4095;
    int n = rem >> 6, m = rem & 63;             // n = query, m = key
    int di = (n >> 3) - (m >> 3);
    int dj = (n & 7)  - (m & 7);
    float fdi = copysignf(log1pf(fabsf((float)di)), (float)di);
    float fdj = copysignf(log1pf(fabsf((float)dj)), (float)dj);
    float acc = m2b[hh];
    for (int k = 0; k < 256; ++k) {
        float tv = fdi * m1w[2*k] + fdj * m1w[2*k+1] + m1b[k];
        float g  = 0.5f * tv * (1.0f + erff(tv * 0.70710678118654752f));
        acc = fmaf(g, m2w[hh*256 + k], acc);
    }
    biasS[hh*4096 + n*64 + m] = acc * INV_SCALE;
}

// ---------------------------------------------------------------- conv weight pre-pack
__global__ __launch_bounds__(64) void k_wprep(
    const float* __restrict__ cw, u16* __restrict__ Bfrag)
{
    int ks   = blockIdx.x;        // 0..161 = (ck*9+tap)*6+nt
    int lane = threadIdx.x;
    int nt    = ks % 6;
    int kstep = ks / 6;
    int tap   = kstep % 9;
    int ck    = kstep / 9;
    int dy = tap / 3, dx = tap % 3;
    int cout = nt*16 + (lane & 15);
    int cin0 = ck*32 + (lane >> 4)*8;
    u16* dst = Bfrag + (size_t)ks*512 + lane*8;
    #pragma unroll
    for (int j = 0; j < 8; ++j)
        dst[j] = f2bf(cw[((size_t)(cout*96 + cin0 + j))*9 + dy*3 + dx]);
}

// ---------------------------------------------------------------- QKV weight pre-pack
__global__ __launch_bounds__(64) void k_wprep_qkv(
    const float* __restrict__ qkw, const float* __restrict__ vw,
    u16* __restrict__ BfragQ)
{
    int ks   = blockIdx.x;        // 0..53 = kstep*18 + nt
    int lane = threadIdx.x;
    int nt    = ks % 18;
    int kstep = ks / 18;
    int o     = nt*16 + (lane & 15);
    int cin0  = kstep*32 + (lane >> 4)*8;
    const float* src = (o < 192) ? (qkw + (size_t)o*96 + cin0)
                                 : (vw + (size_t)(o - 192)*96 + cin0);
    u16* dst = BfragQ + (size_t)ks*512 + lane*8;
    #pragma unroll
    for (int j = 0; j < 8; ++j) dst[j] = f2bf(src[j]);
}

// ---------------------------------------------------------------- proj weight pre-pack
__global__ __launch_bounds__(64) void k_wprep_proj(
    const float* __restrict__ pw, u16* __restrict__ BfragP)
{
    int ks   = blockIdx.x;        // 0..17 = kstep*6 + nt
    int lane = threadIdx.x;
    int nt    = ks % 6;
    int kstep = ks / 6;
    int o     = nt*16 + (lane & 15);
    int cin0  = kstep*32 + (lane >> 4)*8;
    u16* dst = BfragP + (size_t)ks*512 + lane*8;
    #pragma unroll
    for (int j = 0; j < 8; ++j) dst[j] = f2bf(pw[(size_t)o*96 + cin0 + j]);
}

// ---------------------------------------------------------------- QKV 1x1 conv (MFMA, fused x-transpose)
// block = 256 px. Stage x tile (96 ch, fp32 ch-major) -> LDS bf16 pixel-major once,
// then 3 og passes x (3 ksteps x 4mt x 6nt MFMA). out: qkv[b*px][288] bf16.
__global__ __launch_bounds__(256, 2) void k_qkv(
    const float* __restrict__ x, const u16* __restrict__ BfragQ,
    const float* __restrict__ qkb, const float* __restrict__ vb,
    u16* __restrict__ qkv)
{
    int tile = blockIdx.x;                 // 0..2047
    int b    = tile >> 8;
    int pix0 = (tile & 255) * 256;
    size_t px0 = (size_t)tile * 256;       // = b*NPX + pix0
    int t    = threadIdx.x;

    __shared__ u16 xs[256 * HALO_PITCH];   // 53,248 B

    // stage: thread t handles pixel pix0+t, all 96 channels
    {
        const float* xb = x + (size_t)b*96*NPX + pix0 + t;
        u16* xrow = xs + t * HALO_PITCH;
        float v[96];
        #pragma unroll
        for (int c = 0; c < 96; ++c) v[c] = xb[(size_t)c * NPX];
        #pragma unroll
        for (int oct = 0; oct < 12; ++oct) {
            uint4 o;
            o.x = pk2bf(v[oct*8+0], v[oct*8+1]);
            o.y = pk2bf(v[oct*8+2], v[oct*8+3]);
            o.z = pk2bf(v[oct*8+4], v[oct*8+5]);
            o.w = pk2bf(v[oct*8+6], v[oct*8+7]);
            *(uint4*)(xrow + oct*8) = o;
        }
    }
    __syncthreads();

    int wv   = __builtin_amdgcn_readfirstlane(t >> 6);
    int lane = t & 63;
    int lc   = lane & 15;
    int kg   = lane >> 4;

    const u16* bbase = BfragQ + lane*8;

    #pragma unroll 1
    for (int og = 0; og < 3; ++og) {
        f32x4 acc[4][6] = {};
        #pragma unroll
        for (int kstep = 0; kstep < 3; ++kstep) {
            bf16x8 bF[6];
            #pragma unroll
            for (int nt = 0; nt < 6; ++nt)
                bF[nt] = *(const bf16x8*)(bbase + (size_t)(kstep*18 + og*6 + nt)*512);
            #pragma unroll
            for (int mt = 0; mt < 4; ++mt) {
                bf16x8 aF = *(const bf16x8*)(xs + (wv*64 + mt*16 + lc)*HALO_PITCH + kstep*32 + kg*8);
                #pragma unroll
                for (int nt = 0; nt < 6; ++nt)
                    acc[mt][nt] = __builtin_amdgcn_mfma_f32_16x16x32_bf16(aF, bF[nt], acc[mt][nt], 0, 0, 0);
            }
        }

        float bv[6];
        #pragma unroll
        for (int nt = 0; nt < 6; ++nt) {
            int o = og*96 + nt*16 + lc;
            bv[nt] = (o < 192) ? qkb[o] : vb[o - 192];
        }

        #pragma unroll
        for (int mt = 0; mt < 4; ++mt) {
            #pragma unroll
            for (int r = 0; r < 4; ++r) {
                size_t px = px0 + wv*64 + mt*16 + kg*4 + r;
                u16* qp = qkv + px*288 + og*96 + lc;
                #pragma unroll
                for (int nt = 0; nt < 6; ++nt)
                    qp[nt*16] = f2bf(acc[mt][nt][r] + bv[nt]);
            }
        }
    }
}

// ---------------------------------------------------------------- window attention (MFMA)
// 1 wave per window, 4 waves/block. Swapped QK^T: D[key][q] = mfma(K, Q, bias/scale).
__global__ __launch_bounds__(256, 2) void k_attn(
    const u16* __restrict__ qkv, const float* __restrict__ biasS,
    u16* __restrict__ att)
{
    __shared__ u16 lds[27648];           // 4 waves x (P 64x72 + Vt 32x72)
    int t    = threadIdx.x;
    int wv   = __builtin_amdgcn_readfirstlane(t >> 6);
    int lane = t & 63;
    int lc   = lane & 15;
    int kg   = lane >> 4;

    u16* Plds = lds + wv * 6912;         // [64][72] bf16
    u16* Vlds = Plds + 4608;             // [32][72] bf16

    int win = blockIdx.x * 4 + wv;       // 0..8711
    int b   = win / 1089;
    int wr  = win - b * 1089;
    int wy  = wr / NWIN;
    int wx  = wr - wy * NWIN;

    int py = wy*8 + (lane >> 3) - 4;
    int px = wx*8 + (lane & 7)  - 4;
    int iy = refl(py, IMG), ix = refl(px, IMG);
    int pxoff = b*NPX + iy*256 + ix;
    int vpx = (py >= 0 && py < IMG && px >= 0 && px < IMG) ? pxoff : (int)(pxoff | 0x80000000u);

    int pxA[4];
    #pragma unroll
    for (int mt = 0; mt < 4; ++mt)
        pxA[mt] = __builtin_amdgcn_ds_bpermute((16*mt + lc)*4, vpx) & 0x7fffffff;

    #pragma unroll 1
    for (int h = 0; h < 3; ++h) {
        // V rows -> Vt LDS (transposed): Vt[c][key], key = lane
        {
            const u16* vrow = qkv + (size_t)pxoff*288 + 192 + h*32;
            #pragma unroll
            for (int g = 0; g < 4; ++g) {
                bf16x8 vv = *(const bf16x8*)(vrow + g*8);
                #pragma unroll
                for (int j = 0; j < 8; ++j)
                    Vlds[(g*8 + j)*72 + lane] = (u16)vv[j];
            }
        }

        bf16x8 afr[4], bfr[4];
        #pragma unroll
        for (int mt = 0; mt < 4; ++mt) {
            afr[mt] = *(const bf16x8*)(qkv + (size_t)pxA[mt]*288 + 96 + h*32 + kg*8);
            bfr[mt] = *(const bf16x8*)(qkv + (size_t)pxA[mt]*288 +      h*32 + kg*8);
        }

        f32x4 acc[4][4];
        const float* bb = biasS + h*4096 + lc*64 + 4*kg;
        #pragma unroll
        for (int nt = 0; nt < 4; ++nt)
            #pragma unroll
            for (int mt = 0; mt < 4; ++mt)
                acc[mt][nt] = *(const f32x4*)(bb + nt*1024 + mt*16);

        #pragma unroll
        for (int mt = 0; mt < 4; ++mt)
            #pragma unroll
            for (int nt = 0; nt < 4; ++nt)
                acc[mt][nt] = __builtin_amdgcn_mfma_f32_16x16x32_bf16(afr[mt], bfr[nt], acc[mt][nt], 0, 0, 0);

        #pragma unroll
        for (int nt = 0; nt < 4; ++nt) {
            float m = acc[0][nt][0];
            #pragma unroll
            for (int mt = 0; mt < 4; ++mt)
                #pragma unroll
                for (int r = 0; r < 4; ++r)
                    m = fmaxf(m, acc[mt][nt][r]);
            m = fmaxf(m, __shfl_xor(m, 16));
            m = fmaxf(m, __shfl_xor(m, 32));
            float s = 0.f;
            #pragma unroll
            for (int mt = 0; mt < 4; ++mt)
                #pragma unroll
                for (int r = 0; r < 4; ++r) {
                    float p = __expf((acc[mt][nt][r] - m) * ATT_SCALE);
                    acc[mt][nt][r] = p;
                    s += p;
                }
            s += __shfl_xor(s, 16);
            s += __shfl_xor(s, 32);
            float inv = 1.0f / s;
            #pragma unroll
            for (int mt = 0; mt < 4; ++mt)
                #pragma unroll
                for (int r = 0; r < 4; ++r)
                    acc[mt][nt][r] *= inv;
        }

        #pragma unroll
        for (int nt = 0; nt < 4; ++nt)
            #pragma unroll
            for (int mt = 0; mt < 4; ++mt) {
                uint2 pk;
                pk.x = pk2bf(acc[mt][nt][0], acc[mt][nt][1]);
                pk.y = pk2bf(acc[mt][nt][2], acc[mt][nt][3]);
                *(uint2*)(Plds + (16*nt + lc)*72 + 16*mt + 4*kg) = pk;
            }

        f32x4 oacc[4][2] = {};
        #pragma unroll
        for (int s = 0; s < 2; ++s) {
            bf16x8 vb2[2];
            #pragma unroll
            for (int ntpv = 0; ntpv < 2; ++ntpv)
                vb2[ntpv] = *(const bf16x8*)(Vlds + (16*ntpv + lc)*72 + s*32 + kg*8);
            #pragma unroll
            for (int mtpv = 0; mtpv < 4; ++mtpv) {
                bf16x8 pa = *(const bf16x8*)(Plds + (16*mtpv + lc)*72 + s*32 + kg*8);
                #pragma unroll
                for (int ntpv = 0; ntpv < 2; ++ntpv)
                    oacc[mtpv][ntpv] = __builtin_amdgcn_mfma_f32_16x16x32_bf16(pa, vb2[ntpv], oacc[mtpv][ntpv], 0, 0, 0);
            }
        }

        #pragma unroll
        for (int mtpv = 0; mtpv < 4; ++mtpv)
            #pragma unroll
            for (int rr = 0; rr < 4; ++rr) {
                int vp = __builtin_amdgcn_ds_bpermute((16*mtpv + 4*kg + rr)*4, vpx);
                if (vp >= 0) {
                    u16* op = att + (size_t)vp*96 + h*32 + lc;
                    op[0]  = f2bf(oacc[mtpv][0][rr]);
                    op[16] = f2bf(oacc[mtpv][1][rr]);
                }
            }
    }
}

// ---------------------------------------------------------------- 3x3 conv + attn add (MFMA)
__global__ __launch_bounds__(256, 2) void k_conv(
    const u16* __restrict__ qkv, const u16* __restrict__ att,
    const u16* __restrict__ Bfrag, const float* __restrict__ cb,
    u16* __restrict__ S)
{
    int tile = blockIdx.x;              // 0..2047
    int b    = tile >> 8;
    int tr   = tile & 255;              // 32 row-tiles x 8 col-tiles
    int ty0  = (tr >> 3) * 8;
    int tx0  = (tr & 7) * 32;
    int t    = threadIdx.x;

    __shared__ u16 vt[340 * HALO_PITCH];   // 70,720 B

    for (int p = t; p < 340; p += 256) {
        int hr = p / 34;
        int hc = p - hr * 34;
        int gy = refl(ty0 - 1 + hr, IMG);
        int gx = refl(tx0 - 1 + hc, IMG);
        const uint4* src = (const uint4*)(qkv + ((size_t)(b*NPX + gy*256 + gx))*288 + 192);
        uint4* dst = (uint4*)(vt + p * HALO_PITCH);
        #pragma unroll
        for (int q = 0; q < 12; ++q) dst[q] = src[q];
    }
    __syncthreads();

    int wv   = __builtin_amdgcn_readfirstlane(t >> 6);
    int lane = t & 63;
    int lc   = lane & 15;
    int kg   = lane >> 4;

    int abase[4];
    #pragma unroll
    for (int mt = 0; mt < 4; ++mt) {
        int r_mt = 2*wv + (mt >> 1);
        int c_mt = (mt & 1) * 16;
        abase[mt] = (r_mt*34 + c_mt + lc) * HALO_PITCH + kg*8;
    }

    f32x4 acc[4][6] = {};

    const u16* bfr = Bfrag + lane*8;
    #pragma unroll 1
    for (int ck = 0; ck < 3; ++ck) {
        const u16* bck = bfr + ck * 27648;
        int aoff = ck * 32;
        #pragma unroll
        for (int tap = 0; tap < 9; ++tap) {
            const int dy = tap / 3, dx = tap % 3;
            bf16x8 bF[6];
            #pragma unroll
            for (int nt = 0; nt < 6; ++nt)
                bF[nt] = *(const bf16x8*)(bck + (tap*6 + nt)*512);
            #pragma unroll
            for (int mt = 0; mt < 4; ++mt) {
                bf16x8 aF = *(const bf16x8*)(vt + abase[mt] + aoff + (dy*34 + dx)*HALO_PITCH);
                #pragma unroll
                for (int nt = 0; nt < 6; ++nt)
                    acc[mt][nt] = __builtin_amdgcn_mfma_f32_16x16x32_bf16(aF, bF[nt], acc[mt][nt], 0, 0, 0);
            }
        }
    }

    float cbv[6];
    #pragma unroll
    for (int nt = 0; nt < 6; ++nt) cbv[nt] = cb[nt*16 + lc];

    #pragma unroll
    for (int mt = 0; mt < 4; ++mt) {
        int r_mt = 2*wv + (mt >> 1);
        int c_mt = (mt & 1) * 16;
        int y    = ty0 + r_mt;
        #pragma unroll
        for (int r = 0; r < 4; ++r) {
            int x = tx0 + c_mt + kg*4 + r;
            size_t pbase = ((size_t)(b*NPX + y*256 + x))*96 + lc;
            #pragma unroll
            for (int nt = 0; nt < 6; ++nt) {
                float v = acc[mt][nt][r] + cbv[nt] + bf2f(att[pbase + nt*16]);
                S[pbase + nt*16] = f2bf(v);
            }
        }
    }
}

// ---------------------------------------------------------------- proj 1x1 conv (MFMA)
// block = 256 px, wave = 64 px x 96 outs. A-frags direct from S (pixel-major bf16).
__global__ __launch_bounds__(256, 2) void k_proj(
    const u16* __restrict__ S, const u16* __restrict__ BfragP,
    const float* __restrict__ pb, float* __restrict__ out)
{
    int tile = blockIdx.x;                 // 0..2047
    int b    = tile >> 8;
    int pix0 = (tile & 255) * 256;
    size_t px0 = (size_t)tile * 256;
    int t    = threadIdx.x;
    int wv   = __builtin_amdgcn_readfirstlane(t >> 6);
    int lane = t & 63;
    int lc   = lane & 15;
    int kg   = lane >> 4;

    f32x4 acc[4][6] = {};
    const u16* arow  = S + (px0 + wv*64 + lc)*96 + kg*8;
    const u16* bbase = BfragP + lane*8;

    #pragma unroll
    for (int kstep = 0; kstep < 3; ++kstep) {
        bf16x8 bF[6];
        #pragma unroll
        for (int nt = 0; nt < 6; ++nt)
            bF[nt] = *(const bf16x8*)(bbase + (size_t)(kstep*6 + nt)*512);
        #pragma unroll
        for (int mt = 0; mt < 4; ++mt) {
            bf16x8 aF = *(const bf16x8*)(arow + (size_t)mt*16*96 + kstep*32);
            #pragma unroll
            for (int nt = 0; nt < 6; ++nt)
                acc[mt][nt] = __builtin_amdgcn_mfma_f32_16x16x32_bf16(aF, bF[nt], acc[mt][nt], 0, 0, 0);
        }
    }

    float bv[6];
    #pragma unroll
    for (int nt = 0; nt < 6; ++nt) bv[nt] = pb[nt*16 + lc];

    float* ob = out + (size_t)b*96*NPX;
    #pragma unroll
    for (int mt = 0; mt < 4; ++mt) {
        #pragma unroll
        for (int r = 0; r < 4; ++r) {
            int pxi = pix0 + wv*64 + mt*16 + kg*4 + r;
            #pragma unroll
            for (int nt = 0; nt < 6; ++nt)
                ob[(size_t)(nt*16 + lc)*NPX + pxi] = acc[mt][nt][r] + bv[nt];
        }
    }
}

// ----------------------------------------------------------------
extern "C" void kernel_launch(void* const* d_in, const int* in_sizes, int n_in,
                              void* d_out, int out_size, void* d_ws, size_t ws_size,
                              hipStream_t stream)
{
    const float* x      = (const float*)d_in[0];
    const float* V_w    = (const float*)d_in[1];
    const float* V_b    = (const float*)d_in[2];
    const float* QK_w   = (const float*)d_in[3];
    const float* QK_b   = (const float*)d_in[4];
    const float* conv_w = (const float*)d_in[5];
    const float* conv_b = (const float*)d_in[6];
    const float* proj_w = (const float*)d_in[7];
    const float* proj_b = (const float*)d_in[8];
    const float* m1_w   = (const float*)d_in[9];
    const float* m1_b   = (const float*)d_in[10];
    const float* m2_w   = (const float*)d_in[11];
    const float* m2_b   = (const float*)d_in[12];
    float* out = (float*)d_out;

    char* ws = (char*)d_ws;
    float* biasS = (float*)ws;                                      // 49152 B
    u16* qkvb = (u16*)(ws + 49152);                                 // 301989888 B
    u16* attb = (u16*)(ws + 49152 + 301989888);                     // 100663296 B
    u16* sbuf = (u16*)(ws + 49152 + 301989888 + 100663296);         // 100663296 B

    // conv/qkv weight fragments live at the head of d_out (consumed by k_conv /
    // k_qkv, which finish before k_proj starts writing d_out -- stream order).
    char* ob = (char*)d_out;
    u16* Bfrag  = (u16*)ob;                    // 165,888 B
    u16* BfragQ = (u16*)(ob + (1 << 20));      //  55,296 B
    // proj fragments CANNOT live in d_out (k_proj reads them while writing out)
    // -> reuse head of attb, which is dead after k_conv; prep launched post-conv.
    u16* BfragP = (u16*)attb;                  //  18,432 B

    hipLaunchKernelGGL(k_wprep,      dim3(162),     dim3(64),  0, stream, conv_w, Bfrag);
    hipLaunchKernelGGL(k_wprep_qkv,  dim3(54),      dim3(64),  0, stream, QK_w, V_w, BfragQ);
    hipLaunchKernelGGL(k_bias,       dim3(48),      dim3(256), 0, stream, m1_w, m1_b, m2_w, m2_b, biasS);
    hipLaunchKernelGGL(k_qkv,        dim3(2048),    dim3(256), 0, stream, x, BfragQ, QK_b, V_b, qkvb);
    hipLaunchKernelGGL(k_attn,       dim3(2178),    dim3(256), 0, stream, qkvb, biasS, attb);
    hipLaunchKernelGGL(k_conv,       dim3(2048),    dim3(256), 0, stream, qkvb, attb, Bfrag, conv_b, sbuf);
    hipLaunchKernelGGL(k_wprep_proj, dim3(18),      dim3(64),  0, stream, proj_w, BfragP);
    hipLaunchKernelGGL(k_proj,       dim3(2048),    dim3(256), 0, stream, sbuf, BfragP, proj_b, out);
}

// Round 8
// 523.820 us; speedup vs baseline: 9.5903x; 1.1296x over previous
//
#include <hip/hip_runtime.h>
#include <cstdint>

using u16 = unsigned short;
using u32 = unsigned int;
using f32x4  = __attribute__((ext_vector_type(4))) float;
using bf16x8 = __attribute__((ext_vector_type(8))) short;

#define NHEADS 3
#define WSZ 8
#define IMG 256
#define NPX 65536          // pixels per image
#define NWIN 33            // windows per side
#define ATT_SCALE 0.17677669529663687f
#define INV_SCALE 5.656854249492381f
#define HALO_PITCH 104     // u16 per halo pixel (208 B: 96 ch + 8 pad -> conflict-free)

__device__ __forceinline__ int refl(int i, int n) {
    return i < 0 ? -i : (i >= n ? 2*n - 2 - i : i);
}
__device__ __forceinline__ float bflo(u32 u){ union{u32 i; float f;} x; x.i = u << 16; return x.f; }
__device__ __forceinline__ float bfhi(u32 u){ union{u32 i; float f;} x; x.i = u & 0xffff0000u; return x.f; }
__device__ __forceinline__ float bf2f(u16 v){ union{u32 i; float f;} x; x.i = ((u32)v) << 16; return x.f; }
__device__ __forceinline__ u16 f2bf(float f){
    union{float f; u32 i;} x; x.f = f;
    u32 r = x.i + 0x7fffu + ((x.i >> 16) & 1u);
    return (u16)(r >> 16);
}
__device__ __forceinline__ u32 pk2bf(float a, float b){
    return (u32)f2bf(a) | ((u32)f2bf(b) << 16);
}

// ---------------------------------------------------------------- bias table
// biasS[h][q][key] = bias[h][q][key] / ATT_SCALE   (scale folded into exp arg)
__global__ __launch_bounds__(256) void k_bias(
    const float* __restrict__ m1w, const float* __restrict__ m1b,
    const float* __restrict__ m2w, const float* __restrict__ m2b,
    float* __restrict__ biasS)
{
    int idx = blockIdx.x * 256 + threadIdx.x;   // 0..12287
    int hh  = idx >> 12;
    int rem = idx & 4095;
    int n = rem >> 6, m = rem & 63;             // n = query, m = key
    int di = (n >> 3) - (m >> 3);
    int dj = (n & 7)  - (m & 7);
    float fdi = copysignf(log1pf(fabsf((float)di)), (float)di);
    float fdj = copysignf(log1pf(fabsf((float)dj)), (float)dj);
    float acc = m2b[hh];
    for (int k = 0; k < 256; ++k) {
        float tv = fdi * m1w[2*k] + fdj * m1w[2*k+1] + m1b[k];
        float g  = 0.5f * tv * (1.0f + erff(tv * 0.70710678118654752f));
        acc = fmaf(g, m2w[hh*256 + k], acc);
    }
    biasS[hh*4096 + n*64 + m] = acc * INV_SCALE;
}

// ---------------------------------------------------------------- conv weight pre-pack
__global__ __launch_bounds__(64) void k_wprep(
    const float* __restrict__ cw, u16* __restrict__ Bfrag)
{
    int ks   = blockIdx.x;        // 0..161 = (ck*9+tap)*6+nt
    int lane = threadIdx.x;
    int nt    = ks % 6;
    int kstep = ks / 6;
    int tap   = kstep % 9;
    int ck    = kstep / 9;
    int dy = tap / 3, dx = tap % 3;
    int cout = nt*16 + (lane & 15);
    int cin0 = ck*32 + (lane >> 4)*8;
    u16* dst = Bfrag + (size_t)ks*512 + lane*8;
    #pragma unroll
    for (int j = 0; j < 8; ++j)
        dst[j] = f2bf(cw[((size_t)(cout*96 + cin0 + j))*9 + dy*3 + dx]);
}

// ---------------------------------------------------------------- QKV weight pre-pack
__global__ __launch_bounds__(64) void k_wprep_qkv(
    const float* __restrict__ qkw, const float* __restrict__ vw,
    u16* __restrict__ BfragQ)
{
    int ks   = blockIdx.x;        // 0..53 = kstep*18 + nt
    int lane = threadIdx.x;
    int nt    = ks % 18;
    int kstep = ks / 18;
    int o     = nt*16 + (lane & 15);
    int cin0  = kstep*32 + (lane >> 4)*8;
    const float* src = (o < 192) ? (qkw + (size_t)o*96 + cin0)
                                 : (vw + (size_t)(o - 192)*96 + cin0);
    u16* dst = BfragQ + (size_t)ks*512 + lane*8;
    #pragma unroll
    for (int j = 0; j < 8; ++j) dst[j] = f2bf(src[j]);
}

// ---------------------------------------------------------------- proj weight pre-pack
__global__ __launch_bounds__(64) void k_wprep_proj(
    const float* __restrict__ pw, u16* __restrict__ BfragP)
{
    int ks   = blockIdx.x;        // 0..17 = kstep*6 + nt
    int lane = threadIdx.x;
    int nt    = ks % 6;
    int kstep = ks / 6;
    int o     = nt*16 + (lane & 15);
    int cin0  = kstep*32 + (lane >> 4)*8;
    u16* dst = BfragP + (size_t)ks*512 + lane*8;
    #pragma unroll
    for (int j = 0; j < 8; ++j) dst[j] = f2bf(pw[(size_t)o*96 + cin0 + j]);
}

// ---------------------------------------------------------------- QKV 1x1 conv (MFMA, fused x-transpose)
__global__ __launch_bounds__(256, 2) void k_qkv(
    const float* __restrict__ x, const u16* __restrict__ BfragQ,
    const float* __restrict__ qkb, const float* __restrict__ vb,
    u16* __restrict__ qkv)
{
    int tile = blockIdx.x;                 // 0..2047
    int b    = tile >> 8;
    int pix0 = (tile & 255) * 256;
    size_t px0 = (size_t)tile * 256;       // = b*NPX + pix0
    int t    = threadIdx.x;

    __shared__ u16 xs[256 * HALO_PITCH];   // 53,248 B

    {
        const float* xb = x + (size_t)b*96*NPX + pix0 + t;
        u16* xrow = xs + t * HALO_PITCH;
        float v[96];
        #pragma unroll
        for (int c = 0; c < 96; ++c) v[c] = xb[(size_t)c * NPX];
        #pragma unroll
        for (int oct = 0; oct < 12; ++oct) {
            uint4 o;
            o.x = pk2bf(v[oct*8+0], v[oct*8+1]);
            o.y = pk2bf(v[oct*8+2], v[oct*8+3]);
            o.z = pk2bf(v[oct*8+4], v[oct*8+5]);
            o.w = pk2bf(v[oct*8+6], v[oct*8+7]);
            *(uint4*)(xrow + oct*8) = o;
        }
    }
    __syncthreads();

    int wv   = __builtin_amdgcn_readfirstlane(t >> 6);
    int lane = t & 63;
    int lc   = lane & 15;
    int kg   = lane >> 4;

    const u16* bbase = BfragQ + lane*8;

    #pragma unroll 1
    for (int og = 0; og < 3; ++og) {
        f32x4 acc[4][6] = {};
        #pragma unroll
        for (int kstep = 0; kstep < 3; ++kstep) {
            bf16x8 bF[6];
            #pragma unroll
            for (int nt = 0; nt < 6; ++nt)
                bF[nt] = *(const bf16x8*)(bbase + (size_t)(kstep*18 + og*6 + nt)*512);
            #pragma unroll
            for (int mt = 0; mt < 4; ++mt) {
                bf16x8 aF = *(const bf16x8*)(xs + (wv*64 + mt*16 + lc)*HALO_PITCH + kstep*32 + kg*8);
                #pragma unroll
                for (int nt = 0; nt < 6; ++nt)
                    acc[mt][nt] = __builtin_amdgcn_mfma_f32_16x16x32_bf16(aF, bF[nt], acc[mt][nt], 0, 0, 0);
            }
        }

        float bv[6];
        #pragma unroll
        for (int nt = 0; nt < 6; ++nt) {
            int o = og*96 + nt*16 + lc;
            bv[nt] = (o < 192) ? qkb[o] : vb[o - 192];
        }

        #pragma unroll
        for (int mt = 0; mt < 4; ++mt) {
            #pragma unroll
            for (int r = 0; r < 4; ++r) {
                size_t px = px0 + wv*64 + mt*16 + kg*4 + r;
                u16* qp = qkv + px*288 + og*96 + lc;
                #pragma unroll
                for (int nt = 0; nt < 6; ++nt)
                    qp[nt*16] = f2bf(acc[mt][nt][r] + bv[nt]);
            }
        }
    }
}

// ---------------------------------------------------------------- window attention (MFMA 16x16, proven R6 version)
// 1 wave per window, 4 waves/block. Swapped QK^T: D[key][q] = mfma(K, Q, bias/scale).
__global__ __launch_bounds__(256, 2) void k_attn(
    const u16* __restrict__ qkv, const float* __restrict__ biasS,
    u16* __restrict__ att)
{
    __shared__ u16 lds[27648];           // 4 waves x (P 64x72 + Vt 32x72)
    int t    = threadIdx.x;
    int wv   = __builtin_amdgcn_readfirstlane(t >> 6);
    int lane = t & 63;
    int lc   = lane & 15;
    int kg   = lane >> 4;

    u16* Plds = lds + wv * 6912;         // [64][72] bf16
    u16* Vlds = Plds + 4608;             // [32][72] bf16

    int win = blockIdx.x * 4 + wv;       // 0..8711
    int b   = win / 1089;
    int wr  = win - b * 1089;
    int wy  = wr / NWIN;
    int wx  = wr - wy * NWIN;

    int py = wy*8 + (lane >> 3) - 4;
    int px = wx*8 + (lane & 7)  - 4;
    int iy = refl(py, IMG), ix = refl(px, IMG);
    int pxoff = b*NPX + iy*256 + ix;
    int vpx = (py >= 0 && py < IMG && px >= 0 && px < IMG) ? pxoff : (int)(pxoff | 0x80000000u);

    int pxA[4];
    #pragma unroll
    for (int mt = 0; mt < 4; ++mt)
        pxA[mt] = __builtin_amdgcn_ds_bpermute((16*mt + lc)*4, vpx) & 0x7fffffff;

    #pragma unroll 1
    for (int h = 0; h < 3; ++h) {
        // V rows -> Vt LDS (transposed): Vt[c][key=lane]
        {
            const u16* vrow = qkv + (size_t)pxoff*288 + 192 + h*32;
            #pragma unroll
            for (int g = 0; g < 4; ++g) {
                bf16x8 vv = *(const bf16x8*)(vrow + g*8);
                #pragma unroll
                for (int j = 0; j < 8; ++j)
                    Vlds[(g*8 + j)*72 + lane] = (u16)vv[j];
            }
        }

        bf16x8 afr[4], bfr[4];
        #pragma unroll
        for (int mt = 0; mt < 4; ++mt) {
            afr[mt] = *(const bf16x8*)(qkv + (size_t)pxA[mt]*288 + 96 + h*32 + kg*8);
            bfr[mt] = *(const bf16x8*)(qkv + (size_t)pxA[mt]*288 +      h*32 + kg*8);
        }

        f32x4 acc[4][4];
        const float* bb = biasS + h*4096 + lc*64 + 4*kg;
        #pragma unroll
        for (int nt = 0; nt < 4; ++nt)
            #pragma unroll
            for (int mt = 0; mt < 4; ++mt)
                acc[mt][nt] = *(const f32x4*)(bb + nt*1024 + mt*16);

        #pragma unroll
        for (int mt = 0; mt < 4; ++mt)
            #pragma unroll
            for (int nt = 0; nt < 4; ++nt)
                acc[mt][nt] = __builtin_amdgcn_mfma_f32_16x16x32_bf16(afr[mt], bfr[nt], acc[mt][nt], 0, 0, 0);

        #pragma unroll
        for (int nt = 0; nt < 4; ++nt) {
            float m = acc[0][nt][0];
            #pragma unroll
            for (int mt = 0; mt < 4; ++mt)
                #pragma unroll
                for (int r = 0; r < 4; ++r)
                    m = fmaxf(m, acc[mt][nt][r]);
            m = fmaxf(m, __shfl_xor(m, 16));
            m = fmaxf(m, __shfl_xor(m, 32));
            float s = 0.f;
            #pragma unroll
            for (int mt = 0; mt < 4; ++mt)
                #pragma unroll
                for (int r = 0; r < 4; ++r) {
                    float p = __expf((acc[mt][nt][r] - m) * ATT_SCALE);
                    acc[mt][nt][r] = p;
                    s += p;
                }
            s += __shfl_xor(s, 16);
            s += __shfl_xor(s, 32);
            float inv = 1.0f / s;
            #pragma unroll
            for (int mt = 0; mt < 4; ++mt)
                #pragma unroll
                for (int r = 0; r < 4; ++r)
                    acc[mt][nt][r] *= inv;
        }

        #pragma unroll
        for (int nt = 0; nt < 4; ++nt)
            #pragma unroll
            for (int mt = 0; mt < 4; ++mt) {
                uint2 pk;
                pk.x = pk2bf(acc[mt][nt][0], acc[mt][nt][1]);
                pk.y = pk2bf(acc[mt][nt][2], acc[mt][nt][3]);
                *(uint2*)(Plds + (16*nt + lc)*72 + 16*mt + 4*kg) = pk;
            }

        f32x4 oacc[4][2] = {};
        #pragma unroll
        for (int s = 0; s < 2; ++s) {
            bf16x8 vb2[2];
            #pragma unroll
            for (int ntpv = 0; ntpv < 2; ++ntpv)
                vb2[ntpv] = *(const bf16x8*)(Vlds + (16*ntpv + lc)*72 + s*32 + kg*8);
            #pragma unroll
            for (int mtpv = 0; mtpv < 4; ++mtpv) {
                bf16x8 pa = *(const bf16x8*)(Plds + (16*mtpv + lc)*72 + s*32 + kg*8);
                #pragma unroll
                for (int ntpv = 0; ntpv < 2; ++ntpv)
                    oacc[mtpv][ntpv] = __builtin_amdgcn_mfma_f32_16x16x32_bf16(pa, vb2[ntpv], oacc[mtpv][ntpv], 0, 0, 0);
            }
        }

        #pragma unroll
        for (int mtpv = 0; mtpv < 4; ++mtpv)
            #pragma unroll
            for (int rr = 0; rr < 4; ++rr) {
                int vp = __builtin_amdgcn_ds_bpermute((16*mtpv + 4*kg + rr)*4, vpx);
                if (vp >= 0) {
                    u16* op = att + (size_t)vp*96 + h*32 + lc;
                    op[0]  = f2bf(oacc[mtpv][0][rr]);
                    op[16] = f2bf(oacc[mtpv][1][rr]);
                }
            }
    }
}

// ---------------------------------------------------------------- 3x3 conv + attn add + proj (fused, MFMA)
// Phase 1: conv 8x32 px tile from LDS halo (as before), +bias +attn -> bf16 S-tile
//          written to LDS (re-using halo buffer, pitch 104).
// Phase 2: proj MFMA from the S-tile LDS (same read pattern as k_qkv's xs),
//          fp32 out store. Saves the 100MB S write + 100MB S read.
__global__ __launch_bounds__(256, 2) void k_convproj(
    const u16* __restrict__ qkv, const u16* __restrict__ att,
    const u16* __restrict__ Bfrag, const float* __restrict__ cb,
    const u16* __restrict__ BfragP, const float* __restrict__ pb,
    float* __restrict__ out)
{
    int tile = blockIdx.x;              // 0..2047
    int b    = tile >> 8;
    int tr   = tile & 255;              // 32 row-tiles x 8 col-tiles
    int ty0  = (tr >> 3) * 8;
    int tx0  = (tr & 7) * 32;
    int t    = threadIdx.x;

    __shared__ u16 vt[340 * HALO_PITCH];   // 70,720 B; phase-2 reuses as S-tile [256][104]

    for (int p = t; p < 340; p += 256) {
        int hr = p / 34;
        int hc = p - hr * 34;
        int gy = refl(ty0 - 1 + hr, IMG);
        int gx = refl(tx0 - 1 + hc, IMG);
        const uint4* src = (const uint4*)(qkv + ((size_t)(b*NPX + gy*256 + gx))*288 + 192);
        uint4* dst = (uint4*)(vt + p * HALO_PITCH);
        #pragma unroll
        for (int q = 0; q < 12; ++q) dst[q] = src[q];
    }
    __syncthreads();

    int wv   = __builtin_amdgcn_readfirstlane(t >> 6);
    int lane = t & 63;
    int lc   = lane & 15;
    int kg   = lane >> 4;

    int abase[4];
    #pragma unroll
    for (int mt = 0; mt < 4; ++mt) {
        int r_mt = 2*wv + (mt >> 1);
        int c_mt = (mt & 1) * 16;
        abase[mt] = (r_mt*34 + c_mt + lc) * HALO_PITCH + kg*8;
    }

    f32x4 acc[4][6] = {};

    const u16* bfr = Bfrag + lane*8;
    #pragma unroll 1
    for (int ck = 0; ck < 3; ++ck) {
        const u16* bck = bfr + ck * 27648;
        int aoff = ck * 32;
        #pragma unroll
        for (int tap = 0; tap < 9; ++tap) {
            const int dy = tap / 3, dx = tap % 3;
            bf16x8 bF[6];
            #pragma unroll
            for (int nt = 0; nt < 6; ++nt)
                bF[nt] = *(const bf16x8*)(bck + (tap*6 + nt)*512);
            #pragma unroll
            for (int mt = 0; mt < 4; ++mt) {
                bf16x8 aF = *(const bf16x8*)(vt + abase[mt] + aoff + (dy*34 + dx)*HALO_PITCH);
                #pragma unroll
                for (int nt = 0; nt < 6; ++nt)
                    acc[mt][nt] = __builtin_amdgcn_mfma_f32_16x16x32_bf16(aF, bF[nt], acc[mt][nt], 0, 0, 0);
            }
        }
    }

    float cbv[6];
    #pragma unroll
    for (int nt = 0; nt < 6; ++nt) cbv[nt] = cb[nt*16 + lc];

    // all conv reads of vt done -> safe to overwrite with the S-tile
    __syncthreads();

    #pragma unroll
    for (int mt = 0; mt < 4; ++mt) {
        int r_mt = 2*wv + (mt >> 1);
        int c_mt = (mt & 1) * 16;
        int y    = ty0 + r_mt;
        #pragma unroll
        for (int r = 0; r < 4; ++r) {
            int x  = tx0 + c_mt + kg*4 + r;
            int pl = r_mt*32 + c_mt + kg*4 + r;      // local pixel 0..255
            size_t pbase = ((size_t)(b*NPX + y*256 + x))*96 + lc;
            u16* srow = vt + pl * HALO_PITCH + lc;
            #pragma unroll
            for (int nt = 0; nt < 6; ++nt) {
                float v = acc[mt][nt][r] + cbv[nt] + bf2f(att[pbase + nt*16]);
                srow[nt*16] = f2bf(v);
            }
        }
    }
    __syncthreads();

    // phase 2: proj MFMA from S-tile (identical pattern to k_qkv's xs reads)
    f32x4 pacc[4][6] = {};
    const u16* bbase = BfragP + lane*8;
    #pragma unroll
    for (int kstep = 0; kstep < 3; ++kstep) {
        bf16x8 bF[6];
        #pragma unroll
        for (int nt = 0; nt < 6; ++nt)
            bF[nt] = *(const bf16x8*)(bbase + (size_t)(kstep*6 + nt)*512);
        #pragma unroll
        for (int mt = 0; mt < 4; ++mt) {
            bf16x8 aF = *(const bf16x8*)(vt + (wv*64 + mt*16 + lc)*HALO_PITCH + kstep*32 + kg*8);
            #pragma unroll
            for (int nt = 0; nt < 6; ++nt)
                pacc[mt][nt] = __builtin_amdgcn_mfma_f32_16x16x32_bf16(aF, bF[nt], pacc[mt][nt], 0, 0, 0);
        }
    }

    float bv[6];
    #pragma unroll
    for (int nt = 0; nt < 6; ++nt) bv[nt] = pb[nt*16 + lc];

    float* ob = out + (size_t)b*96*NPX;
    #pragma unroll
    for (int mt = 0; mt < 4; ++mt) {
        #pragma unroll
        for (int r = 0; r < 4; ++r) {
            int pl = wv*64 + mt*16 + kg*4 + r;       // local pixel 0..255
            int y  = ty0 + (pl >> 5);
            int x  = tx0 + (pl & 31);
            #pragma unroll
            for (int nt = 0; nt < 6; ++nt)
                ob[(size_t)(nt*16 + lc)*NPX + y*256 + x] = pacc[mt][nt][r] + bv[nt];
        }
    }
}

// ----------------------------------------------------------------
extern "C" void kernel_launch(void* const* d_in, const int* in_sizes, int n_in,
                              void* d_out, int out_size, void* d_ws, size_t ws_size,
                              hipStream_t stream)
{
    const float* x      = (const float*)d_in[0];
    const float* V_w    = (const float*)d_in[1];
    const float* V_b    = (const float*)d_in[2];
    const float* QK_w   = (const float*)d_in[3];
    const float* QK_b   = (const float*)d_in[4];
    const float* conv_w = (const float*)d_in[5];
    const float* conv_b = (const float*)d_in[6];
    const float* proj_w = (const float*)d_in[7];
    const float* proj_b = (const float*)d_in[8];
    const float* m1_w   = (const float*)d_in[9];
    const float* m1_b   = (const float*)d_in[10];
    const float* m2_w   = (const float*)d_in[11];
    const float* m2_b   = (const float*)d_in[12];
    float* out = (float*)d_out;

    char* ws = (char*)d_ws;
    float* biasS = (float*)ws;                                      // 49152 B
    u16* qkvb = (u16*)(ws + 49152);                                 // 301989888 B
    u16* attb = (u16*)(ws + 49152 + 301989888);                     // 100663296 B
    char* scr = ws + 49152 + 301989888 + 100663296;                 // old sbuf region (free)

    // weight fragments now all live in d_ws (d_out is written concurrently
    // with Bfrag/BfragP reads inside the fused k_convproj -> cannot alias).
    u16* Bfrag  = (u16*)scr;                   // 165,888 B
    u16* BfragQ = (u16*)(scr + (1 << 20));     //  55,296 B
    u16* BfragP = (u16*)(scr + (2 << 20));     //  18,432 B

    hipLaunchKernelGGL(k_wprep,      dim3(162),     dim3(64),  0, stream, conv_w, Bfrag);
    hipLaunchKernelGGL(k_wprep_qkv,  dim3(54),      dim3(64),  0, stream, QK_w, V_w, BfragQ);
    hipLaunchKernelGGL(k_wprep_proj, dim3(18),      dim3(64),  0, stream, proj_w, BfragP);
    hipLaunchKernelGGL(k_bias,       dim3(48),      dim3(256), 0, stream, m1_w, m1_b, m2_w, m2_b, biasS);
    hipLaunchKernelGGL(k_qkv,        dim3(2048),    dim3(256), 0, stream, x, BfragQ, QK_b, V_b, qkvb);
    hipLaunchKernelGGL(k_attn,       dim3(2178),    dim3(256), 0, stream, qkvb, biasS, attb);
    hipLaunchKernelGGL(k_convproj,   dim3(2048),    dim3(256), 0, stream, qkvb, attb, Bfrag, conv_b, BfragP, proj_b, out);
}

// Round 9
// 516.418 us; speedup vs baseline: 9.7278x; 1.0143x over previous
//
#include <hip/hip_runtime.h>
#include <cstdint>

using u16 = unsigned short;
using u32 = unsigned int;
using f32x4  = __attribute__((ext_vector_type(4))) float;
using bf16x8 = __attribute__((ext_vector_type(8))) short;

#define NHEADS 3
#define WSZ 8
#define IMG 256
#define NPX 65536          // pixels per image
#define NWIN 33            // windows per side
#define ATT_SCALE 0.17677669529663687f
#define INV_SCALE 5.656854249492381f
#define HALO_PITCH 104     // u16 per halo pixel (208 B: 96 ch + 8 pad -> conflict-free)

__device__ __forceinline__ int refl(int i, int n) {
    return i < 0 ? -i : (i >= n ? 2*n - 2 - i : i);
}
__device__ __forceinline__ float bflo(u32 u){ union{u32 i; float f;} x; x.i = u << 16; return x.f; }
__device__ __forceinline__ float bfhi(u32 u){ union{u32 i; float f;} x; x.i = u & 0xffff0000u; return x.f; }
__device__ __forceinline__ float bf2f(u16 v){ union{u32 i; float f;} x; x.i = ((u32)v) << 16; return x.f; }
__device__ __forceinline__ u16 f2bf(float f){
    union{float f; u32 i;} x; x.f = f;
    u32 r = x.i + 0x7fffu + ((x.i >> 16) & 1u);
    return (u16)(r >> 16);
}
__device__ __forceinline__ u32 pk2bf(float a, float b){
    return (u32)f2bf(a) | ((u32)f2bf(b) << 16);
}

// ---------------------------------------------------------------- bias table
// biasS[h][q][key] = bias[h][q][key] / ATT_SCALE   (scale folded into exp arg)
__global__ __launch_bounds__(256) void k_bias(
    const float* __restrict__ m1w, const float* __restrict__ m1b,
    const float* __restrict__ m2w, const float* __restrict__ m2b,
    float* __restrict__ biasS)
{
    int idx = blockIdx.x * 256 + threadIdx.x;   // 0..12287
    int hh  = idx >> 12;
    int rem = idx & 4095;
    int n = rem >> 6, m = rem & 63;             // n = query, m = key
    int di = (n >> 3) - (m >> 3);
    int dj = (n & 7)  - (m & 7);
    float fdi = copysignf(log1pf(fabsf((float)di)), (float)di);
    float fdj = copysignf(log1pf(fabsf((float)dj)), (float)dj);
    float acc = m2b[hh];
    for (int k = 0; k < 256; ++k) {
        float tv = fdi * m1w[2*k] + fdj * m1w[2*k+1] + m1b[k];
        float g  = 0.5f * tv * (1.0f + erff(tv * 0.70710678118654752f));
        acc = fmaf(g, m2w[hh*256 + k], acc);
    }
    biasS[hh*4096 + n*64 + m] = acc * INV_SCALE;
}

// ---------------------------------------------------------------- conv weight pre-pack
__global__ __launch_bounds__(64) void k_wprep(
    const float* __restrict__ cw, u16* __restrict__ Bfrag)
{
    int ks   = blockIdx.x;        // 0..161 = (ck*9+tap)*6+nt
    int lane = threadIdx.x;
    int nt    = ks % 6;
    int kstep = ks / 6;
    int tap   = kstep % 9;
    int ck    = kstep / 9;
    int dy = tap / 3, dx = tap % 3;
    int cout = nt*16 + (lane & 15);
    int cin0 = ck*32 + (lane >> 4)*8;
    u16* dst = Bfrag + (size_t)ks*512 + lane*8;
    #pragma unroll
    for (int j = 0; j < 8; ++j)
        dst[j] = f2bf(cw[((size_t)(cout*96 + cin0 + j))*9 + dy*3 + dx]);
}

// ---------------------------------------------------------------- QKV weight pre-pack
__global__ __launch_bounds__(64) void k_wprep_qkv(
    const float* __restrict__ qkw, const float* __restrict__ vw,
    u16* __restrict__ BfragQ)
{
    int ks   = blockIdx.x;        // 0..53 = kstep*18 + nt
    int lane = threadIdx.x;
    int nt    = ks % 18;
    int kstep = ks / 18;
    int o     = nt*16 + (lane & 15);
    int cin0  = kstep*32 + (lane >> 4)*8;
    const float* src = (o < 192) ? (qkw + (size_t)o*96 + cin0)
                                 : (vw + (size_t)(o - 192)*96 + cin0);
    u16* dst = BfragQ + (size_t)ks*512 + lane*8;
    #pragma unroll
    for (int j = 0; j < 8; ++j) dst[j] = f2bf(src[j]);
}

// ---------------------------------------------------------------- proj weight pre-pack
__global__ __launch_bounds__(64) void k_wprep_proj(
    const float* __restrict__ pw, u16* __restrict__ BfragP)
{
    int ks   = blockIdx.x;        // 0..17 = kstep*6 + nt
    int lane = threadIdx.x;
    int nt    = ks % 6;
    int kstep = ks / 6;
    int o     = nt*16 + (lane & 15);
    int cin0  = kstep*32 + (lane >> 4)*8;
    u16* dst = BfragP + (size_t)ks*512 + lane*8;
    #pragma unroll
    for (int j = 0; j < 8; ++j) dst[j] = f2bf(pw[(size_t)o*96 + cin0 + j]);
}

// ---------------------------------------------------------------- QKV 1x1 conv (MFMA, fused x-transpose)
__global__ __launch_bounds__(256, 2) void k_qkv(
    const float* __restrict__ x, const u16* __restrict__ BfragQ,
    const float* __restrict__ qkb, const float* __restrict__ vb,
    u16* __restrict__ qkv)
{
    int tile = blockIdx.x;                 // 0..2047
    int b    = tile >> 8;
    int pix0 = (tile & 255) * 256;
    size_t px0 = (size_t)tile * 256;       // = b*NPX + pix0
    int t    = threadIdx.x;

    __shared__ u16 xs[256 * HALO_PITCH];   // 53,248 B

    {
        const float* xb = x + (size_t)b*96*NPX + pix0 + t;
        u16* xrow = xs + t * HALO_PITCH;
        float v[96];
        #pragma unroll
        for (int c = 0; c < 96; ++c) v[c] = xb[(size_t)c * NPX];
        #pragma unroll
        for (int oct = 0; oct < 12; ++oct) {
            uint4 o;
            o.x = pk2bf(v[oct*8+0], v[oct*8+1]);
            o.y = pk2bf(v[oct*8+2], v[oct*8+3]);
            o.z = pk2bf(v[oct*8+4], v[oct*8+5]);
            o.w = pk2bf(v[oct*8+6], v[oct*8+7]);
            *(uint4*)(xrow + oct*8) = o;
        }
    }
    __syncthreads();

    int wv   = __builtin_amdgcn_readfirstlane(t >> 6);
    int lane = t & 63;
    int lc   = lane & 15;
    int kg   = lane >> 4;

    const u16* bbase = BfragQ + lane*8;

    #pragma unroll 1
    for (int og = 0; og < 3; ++og) {
        f32x4 acc[4][6] = {};
        #pragma unroll
        for (int kstep = 0; kstep < 3; ++kstep) {
            bf16x8 bF[6];
            #pragma unroll
            for (int nt = 0; nt < 6; ++nt)
                bF[nt] = *(const bf16x8*)(bbase + (size_t)(kstep*18 + og*6 + nt)*512);
            #pragma unroll
            for (int mt = 0; mt < 4; ++mt) {
                bf16x8 aF = *(const bf16x8*)(xs + (wv*64 + mt*16 + lc)*HALO_PITCH + kstep*32 + kg*8);
                #pragma unroll
                for (int nt = 0; nt < 6; ++nt)
                    acc[mt][nt] = __builtin_amdgcn_mfma_f32_16x16x32_bf16(aF, bF[nt], acc[mt][nt], 0, 0, 0);
            }
        }

        float bv[6];
        #pragma unroll
        for (int nt = 0; nt < 6; ++nt) {
            int o = og*96 + nt*16 + lc;
            bv[nt] = (o < 192) ? qkb[o] : vb[o - 192];
        }

        #pragma unroll
        for (int mt = 0; mt < 4; ++mt) {
            #pragma unroll
            for (int r = 0; r < 4; ++r) {
                size_t px = px0 + wv*64 + mt*16 + kg*4 + r;
                u16* qp = qkv + px*288 + og*96 + lc;
                #pragma unroll
                for (int nt = 0; nt < 6; ++nt)
                    qp[nt*16] = f2bf(acc[mt][nt][r] + bv[nt]);
            }
        }
    }
}

// ---------------------------------------------------------------- window attention (MFMA 16x16, per-q-block pipeline)
// 1 wave per window, 4 waves/block. Swapped QK^T: D[key][q] = mfma(K, Q, bias/scale).
// Per q-block nt: QK(4 MFMA) -> softmax -> P[16][72] LDS -> PV(4 MFMA) -> store.
// P buffer is 4x smaller than computing all q-blocks upfront: LDS 27,648 B/block
// -> 4+ blocks/CU (was 2). Fragment addressing identical to the verified R6 kernel.
__global__ __launch_bounds__(256, 4) void k_attn(
    const u16* __restrict__ qkv, const float* __restrict__ biasS,
    u16* __restrict__ att)
{
    __shared__ u16 lds[4 * 3456];        // 4 waves x (P[16][72] + Vt[32][72])
    int t    = threadIdx.x;
    int wv   = __builtin_amdgcn_readfirstlane(t >> 6);
    int lane = t & 63;
    int lc   = lane & 15;
    int kg   = lane >> 4;

    u16* Plds = lds + wv * 3456;         // [16][72] bf16
    u16* Vlds = Plds + 1152;             // [32][72] bf16

    int win = blockIdx.x * 4 + wv;       // 0..8711
    int b   = win / 1089;
    int wr  = win - b * 1089;
    int wy  = wr / NWIN;
    int wx  = wr - wy * NWIN;

    int py = wy*8 + (lane >> 3) - 4;
    int px = wx*8 + (lane & 7)  - 4;
    int iy = refl(py, IMG), ix = refl(px, IMG);
    int pxoff = b*NPX + iy*256 + ix;
    int vpx = (py >= 0 && py < IMG && px >= 0 && px < IMG) ? pxoff : (int)(pxoff | 0x80000000u);

    int pxA[4];
    #pragma unroll
    for (int mt = 0; mt < 4; ++mt)
        pxA[mt] = __builtin_amdgcn_ds_bpermute((16*mt + lc)*4, vpx) & 0x7fffffff;

    #pragma unroll 1
    for (int h = 0; h < 3; ++h) {
        // V rows -> Vt LDS (transposed): Vt[c][key=lane]
        {
            const u16* vrow = qkv + (size_t)pxoff*288 + 192 + h*32;
            #pragma unroll
            for (int g = 0; g < 4; ++g) {
                bf16x8 vv = *(const bf16x8*)(vrow + g*8);
                #pragma unroll
                for (int j = 0; j < 8; ++j)
                    Vlds[(g*8 + j)*72 + lane] = (u16)vv[j];
            }
        }

        // K A-frags (shared across all q-blocks of this head)
        bf16x8 afr[4];
        #pragma unroll
        for (int mt = 0; mt < 4; ++mt)
            afr[mt] = *(const bf16x8*)(qkv + (size_t)pxA[mt]*288 + 96 + h*32 + kg*8);

        #pragma unroll 1
        for (int nt = 0; nt < 4; ++nt) {
            // Q B-frag for this q-block
            bf16x8 qf = *(const bf16x8*)(qkv + (size_t)pxA[nt]*288 + h*32 + kg*8);

            // C-init = bias/scale at [key=16mt+4kg+r][q=16nt+lc]
            f32x4 acc[4];
            const float* bb = biasS + h*4096 + (size_t)nt*1024 + lc*64 + 4*kg;
            #pragma unroll
            for (int mt = 0; mt < 4; ++mt)
                acc[mt] = *(const f32x4*)(bb + mt*16);

            #pragma unroll
            for (int mt = 0; mt < 4; ++mt)
                acc[mt] = __builtin_amdgcn_mfma_f32_16x16x32_bf16(afr[mt], qf, acc[mt], 0, 0, 0);

            // softmax over keys for q = 16nt+lc
            float m = acc[0][0];
            #pragma unroll
            for (int mt = 0; mt < 4; ++mt)
                #pragma unroll
                for (int r = 0; r < 4; ++r)
                    m = fmaxf(m, acc[mt][r]);
            m = fmaxf(m, __shfl_xor(m, 16));
            m = fmaxf(m, __shfl_xor(m, 32));
            float s = 0.f;
            #pragma unroll
            for (int mt = 0; mt < 4; ++mt)
                #pragma unroll
                for (int r = 0; r < 4; ++r) {
                    float p = __expf((acc[mt][r] - m) * ATT_SCALE);
                    acc[mt][r] = p;
                    s += p;
                }
            s += __shfl_xor(s, 16);
            s += __shfl_xor(s, 32);
            float inv = 1.0f / s;
            #pragma unroll
            for (int mt = 0; mt < 4; ++mt)
                #pragma unroll
                for (int r = 0; r < 4; ++r)
                    acc[mt][r] *= inv;

            // P -> LDS: row = lc (q within block), key = 16mt+4kg+(0..3)
            #pragma unroll
            for (int mt = 0; mt < 4; ++mt) {
                uint2 pk;
                pk.x = pk2bf(acc[mt][0], acc[mt][1]);
                pk.y = pk2bf(acc[mt][2], acc[mt][3]);
                *(uint2*)(Plds + lc*72 + 16*mt + 4*kg) = pk;
            }

            // PV for this q-block: D[q][c] = sum_key P[q][key] * V[key][c]
            f32x4 oacc[2] = {};
            #pragma unroll
            for (int s2 = 0; s2 < 2; ++s2) {
                bf16x8 pa = *(const bf16x8*)(Plds + lc*72 + s2*32 + kg*8);
                #pragma unroll
                for (int ntpv = 0; ntpv < 2; ++ntpv) {
                    bf16x8 vb2 = *(const bf16x8*)(Vlds + (16*ntpv + lc)*72 + s2*32 + kg*8);
                    oacc[ntpv] = __builtin_amdgcn_mfma_f32_16x16x32_bf16(pa, vb2, oacc[ntpv], 0, 0, 0);
                }
            }

            // store: out[q = 16nt+4kg+rr][c = 16ntpv+lc]
            #pragma unroll
            for (int rr = 0; rr < 4; ++rr) {
                int vp = __builtin_amdgcn_ds_bpermute((16*nt + 4*kg + rr)*4, vpx);
                if (vp >= 0) {
                    u16* op = att + (size_t)vp*96 + h*32 + lc;
                    op[0]  = f2bf(oacc[0][rr]);
                    op[16] = f2bf(oacc[1][rr]);
                }
            }
        }
    }
}

// ---------------------------------------------------------------- 3x3 conv + attn add + proj (fused, MFMA)
__global__ __launch_bounds__(256, 2) void k_convproj(
    const u16* __restrict__ qkv, const u16* __restrict__ att,
    const u16* __restrict__ Bfrag, const float* __restrict__ cb,
    const u16* __restrict__ BfragP, const float* __restrict__ pb,
    float* __restrict__ out)
{
    int tile = blockIdx.x;              // 0..2047
    int b    = tile >> 8;
    int tr   = tile & 255;              // 32 row-tiles x 8 col-tiles
    int ty0  = (tr >> 3) * 8;
    int tx0  = (tr & 7) * 32;
    int t    = threadIdx.x;

    __shared__ u16 vt[340 * HALO_PITCH];   // 70,720 B; phase-2 reuses as S-tile [256][104]

    for (int p = t; p < 340; p += 256) {
        int hr = p / 34;
        int hc = p - hr * 34;
        int gy = refl(ty0 - 1 + hr, IMG);
        int gx = refl(tx0 - 1 + hc, IMG);
        const uint4* src = (const uint4*)(qkv + ((size_t)(b*NPX + gy*256 + gx))*288 + 192);
        uint4* dst = (uint4*)(vt + p * HALO_PITCH);
        #pragma unroll
        for (int q = 0; q < 12; ++q) dst[q] = src[q];
    }
    __syncthreads();

    int wv   = __builtin_amdgcn_readfirstlane(t >> 6);
    int lane = t & 63;
    int lc   = lane & 15;
    int kg   = lane >> 4;

    int abase[4];
    #pragma unroll
    for (int mt = 0; mt < 4; ++mt) {
        int r_mt = 2*wv + (mt >> 1);
        int c_mt = (mt & 1) * 16;
        abase[mt] = (r_mt*34 + c_mt + lc) * HALO_PITCH + kg*8;
    }

    f32x4 acc[4][6] = {};

    const u16* bfr = Bfrag + lane*8;
    #pragma unroll 1
    for (int ck = 0; ck < 3; ++ck) {
        const u16* bck = bfr + ck * 27648;
        int aoff = ck * 32;
        #pragma unroll
        for (int tap = 0; tap < 9; ++tap) {
            const int dy = tap / 3, dx = tap % 3;
            bf16x8 bF[6];
            #pragma unroll
            for (int nt = 0; nt < 6; ++nt)
                bF[nt] = *(const bf16x8*)(bck + (tap*6 + nt)*512);
            #pragma unroll
            for (int mt = 0; mt < 4; ++mt) {
                bf16x8 aF = *(const bf16x8*)(vt + abase[mt] + aoff + (dy*34 + dx)*HALO_PITCH);
                #pragma unroll
                for (int nt = 0; nt < 6; ++nt)
                    acc[mt][nt] = __builtin_amdgcn_mfma_f32_16x16x32_bf16(aF, bF[nt], acc[mt][nt], 0, 0, 0);
            }
        }
    }

    float cbv[6];
    #pragma unroll
    for (int nt = 0; nt < 6; ++nt) cbv[nt] = cb[nt*16 + lc];

    // all conv reads of vt done -> safe to overwrite with the S-tile
    __syncthreads();

    #pragma unroll
    for (int mt = 0; mt < 4; ++mt) {
        int r_mt = 2*wv + (mt >> 1);
        int c_mt = (mt & 1) * 16;
        int y    = ty0 + r_mt;
        #pragma unroll
        for (int r = 0; r < 4; ++r) {
            int x  = tx0 + c_mt + kg*4 + r;
            int pl = r_mt*32 + c_mt + kg*4 + r;      // local pixel 0..255
            size_t pbase = ((size_t)(b*NPX + y*256 + x))*96 + lc;
            u16* srow = vt + pl * HALO_PITCH + lc;
            #pragma unroll
            for (int nt = 0; nt < 6; ++nt) {
                float v = acc[mt][nt][r] + cbv[nt] + bf2f(att[pbase + nt*16]);
                srow[nt*16] = f2bf(v);
            }
        }
    }
    __syncthreads();

    // phase 2: proj MFMA from S-tile (identical pattern to k_qkv's xs reads)
    f32x4 pacc[4][6] = {};
    const u16* bbase = BfragP + lane*8;
    #pragma unroll
    for (int kstep = 0; kstep < 3; ++kstep) {
        bf16x8 bF[6];
        #pragma unroll
        for (int nt = 0; nt < 6; ++nt)
            bF[nt] = *(const bf16x8*)(bbase + (size_t)(kstep*6 + nt)*512);
        #pragma unroll
        for (int mt = 0; mt < 4; ++mt) {
            bf16x8 aF = *(const bf16x8*)(vt + (wv*64 + mt*16 + lc)*HALO_PITCH + kstep*32 + kg*8);
            #pragma unroll
            for (int nt = 0; nt < 6; ++nt)
                pacc[mt][nt] = __builtin_amdgcn_mfma_f32_16x16x32_bf16(aF, bF[nt], pacc[mt][nt], 0, 0, 0);
        }
    }

    float bv[6];
    #pragma unroll
    for (int nt = 0; nt < 6; ++nt) bv[nt] = pb[nt*16 + lc];

    float* ob = out + (size_t)b*96*NPX;
    #pragma unroll
    for (int mt = 0; mt < 4; ++mt) {
        #pragma unroll
        for (int r = 0; r < 4; ++r) {
            int pl = wv*64 + mt*16 + kg*4 + r;       // local pixel 0..255
            int y  = ty0 + (pl >> 5);
            int x  = tx0 + (pl & 31);
            #pragma unroll
            for (int nt = 0; nt < 6; ++nt)
                ob[(size_t)(nt*16 + lc)*NPX + y*256 + x] = pacc[mt][nt][r] + bv[nt];
        }
    }
}

// ----------------------------------------------------------------
extern "C" void kernel_launch(void* const* d_in, const int* in_sizes, int n_in,
                              void* d_out, int out_size, void* d_ws, size_t ws_size,
                              hipStream_t stream)
{
    const float* x      = (const float*)d_in[0];
    const float* V_w    = (const float*)d_in[1];
    const float* V_b    = (const float*)d_in[2];
    const float* QK_w   = (const float*)d_in[3];
    const float* QK_b   = (const float*)d_in[4];
    const float* conv_w = (const float*)d_in[5];
    const float* conv_b = (const float*)d_in[6];
    const float* proj_w = (const float*)d_in[7];
    const float* proj_b = (const float*)d_in[8];
    const float* m1_w   = (const float*)d_in[9];
    const float* m1_b   = (const float*)d_in[10];
    const float* m2_w   = (const float*)d_in[11];
    const float* m2_b   = (const float*)d_in[12];
    float* out = (float*)d_out;

    char* ws = (char*)d_ws;
    float* biasS = (float*)ws;                                      // 49152 B
    u16* qkvb = (u16*)(ws + 49152);                                 // 301989888 B
    u16* attb = (u16*)(ws + 49152 + 301989888);                     // 100663296 B
    char* scr = ws + 49152 + 301989888 + 100663296;                 // free region

    u16* Bfrag  = (u16*)scr;                   // 165,888 B
    u16* BfragQ = (u16*)(scr + (1 << 20));     //  55,296 B
    u16* BfragP = (u16*)(scr + (2 << 20));     //  18,432 B

    hipLaunchKernelGGL(k_wprep,      dim3(162),     dim3(64),  0, stream, conv_w, Bfrag);
    hipLaunchKernelGGL(k_wprep_qkv,  dim3(54),      dim3(64),  0, stream, QK_w, V_w, BfragQ);
    hipLaunchKernelGGL(k_wprep_proj, dim3(18),      dim3(64),  0, stream, proj_w, BfragP);
    hipLaunchKernelGGL(k_bias,       dim3(48),      dim3(256), 0, stream, m1_w, m1_b, m2_w, m2_b, biasS);
    hipLaunchKernelGGL(k_qkv,        dim3(2048),    dim3(256), 0, stream, x, BfragQ, QK_b, V_b, qkvb);
    hipLaunchKernelGGL(k_attn,       dim3(2178),    dim3(256), 0, stream, qkvb, biasS, attb);
    hipLaunchKernelGGL(k_convproj,   dim3(2048),    dim3(256), 0, stream, qkvb, attb, Bfrag, conv_b, BfragP, proj_b, out);
}